// Round 2
// baseline (7363.876 us; speedup 1.0000x reference)
//
#include <hip/hip_runtime.h>
#include <hip/hip_bf16.h>
#include <math.h>

#define BB   4
#define SS   1024
#define DDIM 1024
#define HH   16
#define DKK  64
#define DFFF 4096

// ---------- block reductions (256 threads = 4 waves of 64) ----------
__device__ __forceinline__ float block_reduce_sum(float v, float* red, int tid) {
#pragma unroll
    for (int off = 32; off; off >>= 1) v += __shfl_xor(v, off);
    __syncthreads();                       // protect red from prior use
    if ((tid & 63) == 0) red[tid >> 6] = v;
    __syncthreads();
    return red[0] + red[1] + red[2] + red[3];
}
__device__ __forceinline__ float block_reduce_max(float v, float* red, int tid) {
#pragma unroll
    for (int off = 32; off; off >>= 1) v = fmaxf(v, __shfl_xor(v, off));
    __syncthreads();
    if ((tid & 63) == 0) red[tid >> 6] = v;
    __syncthreads();
    return fmaxf(fmaxf(red[0], red[1]), fmaxf(red[2], red[3]));
}

// ---------- generic GEMM: C[M,N] = act(A[M,K] * W[N,K]^T + bias[N]) ----------
// 64x64 tile, 256 threads, 4x4 per thread, fp32 accumulate. M,N,K all %64==0.
template <bool RELU>
__global__ __launch_bounds__(256) void gemm_nt(const float* __restrict__ A,
                                               const float* __restrict__ W,
                                               const float* __restrict__ bias,
                                               float* __restrict__ C,
                                               int M, int N, int K) {
    __shared__ float As[16][65];
    __shared__ float Ws[16][65];
    const int tid = threadIdx.x;
    const int tx = tid & 15, ty = tid >> 4;
    const int bm = blockIdx.y * 64, bn = blockIdx.x * 64;
    float acc[4][4] = {};

    for (int kt = 0; kt < K; kt += 16) {
#pragma unroll
        for (int l = 0; l < 4; l++) {
            int idx = tid * 4 + l;          // 0..1023
            int k = idx & 15, m = idx >> 4; // contiguous k per thread
            As[k][m] = A[(size_t)(bm + m) * K + kt + k];
            Ws[k][m] = W[(size_t)(bn + m) * K + kt + k];
        }
        __syncthreads();
#pragma unroll
        for (int k = 0; k < 16; k++) {
            float a[4], w[4];
#pragma unroll
            for (int u = 0; u < 4; u++) a[u] = As[k][ty + 16 * u];
#pragma unroll
            for (int v = 0; v < 4; v++) w[v] = Ws[k][tx + 16 * v];
#pragma unroll
            for (int u = 0; u < 4; u++)
#pragma unroll
                for (int v = 0; v < 4; v++) acc[u][v] += a[u] * w[v];
        }
        __syncthreads();
    }
#pragma unroll
    for (int u = 0; u < 4; u++) {
        int m = bm + ty + 16 * u;
#pragma unroll
        for (int v = 0; v < 4; v++) {
            int n = bn + tx + 16 * v;
            float r = acc[u][v] + bias[n];
            if (RELU) r = fmaxf(r, 0.f);
            C[(size_t)m * N + n] = r;
        }
    }
}

// ---------- attention, one block per (b,h,i) row ----------
// scores -> softmax#1 -> masked cumsum (scan) -> distance-decay rescale ->
// masked softmax#2 -> attn @ V. All row state in LDS (S=1024 floats).
__global__ __launch_bounds__(256) void attn_row(const float* __restrict__ Q,
                                                const float* __restrict__ Kb,
                                                const float* __restrict__ V,
                                                const float* __restrict__ gammas,
                                                const int* __restrict__ maskp,
                                                float* __restrict__ out) {
    const int row = blockIdx.x;          // b*H*S + h*S + i
    const int i = row & (SS - 1);
    const int h = (row >> 10) & (HH - 1);
    const int b = row >> 14;
    const int mask = *maskp;
    const int tid = threadIdx.x;
    const int lane = tid & 63;
    const int wv = tid >> 6;

    __shared__ float sc[SS];    // raw scores, later rescaled scores
    __shared__ float pr[SS];    // probs / cumsum / final attn
    __shared__ float qs[DKK];
    __shared__ float red[4];
    __shared__ float redv[256];

    const size_t basekv = (size_t)b * SS * DDIM + (size_t)h * DKK;

    if (tid < DKK) qs[tid] = Q[(size_t)(b * SS + i) * DDIM + h * DKK + tid];
    __syncthreads();
    const float qv = qs[lane];

    // scores[j] = q_i . k_j / sqrt(64); one wave per j, coalesced 64-lane load
    for (int j = wv; j < SS; j += 4) {
        float p = qv * Kb[basekv + (size_t)j * DDIM + lane];
#pragma unroll
        for (int off = 32; off; off >>= 1) p += __shfl_xor(p, off);
        if (lane == 0) sc[j] = p * 0.125f;
    }
    __syncthreads();

    // softmax #1 over ALL j (unmasked), normalized, then multiplied by allowed
    float mx = -1e30f;
    for (int idx = tid; idx < SS; idx += 256) mx = fmaxf(mx, sc[idx]);
    mx = block_reduce_max(mx, red, tid);
    float sm = 0.f;
    for (int idx = tid; idx < SS; idx += 256) {
        float e = __expf(sc[idx] - mx);
        pr[idx] = e;
        sm += e;
    }
    sm = block_reduce_sum(sm, red, tid);   // barriers make pr[] visible
    const float inv = 1.f / sm;
    for (int idx = tid; idx < SS; idx += 256) {
        bool allowed = (idx < i + mask);   // j - i < mask
        pr[idx] = allowed ? pr[idx] * inv : 0.f;
    }
    __syncthreads();

    // inclusive scan of pr (Hillis-Steele, 1024 elems, 4 per thread)
    for (int off = 1; off < SS; off <<= 1) {
        float t0[4];
#pragma unroll
        for (int l = 0; l < 4; l++) {
            int idx = tid + l * 256;
            t0[l] = (idx >= off) ? pr[idx - off] : 0.f;
        }
        __syncthreads();
#pragma unroll
        for (int l = 0; l < 4; l++) pr[tid + l * 256] += t0[l];
        __syncthreads();
    }
    const float disttot = pr[SS - 1];

    // distance-decay rescale + causal mask
    float g = gammas[h];
    float sp = (g > 20.f) ? g : log1pf(__expf(g));   // softplus
    const float gamma = -sp;
    for (int idx = tid; idx < SS; idx += 256) {
        bool allowed = (idx < i + mask);
        float pos = fabsf((float)(idx - i));
        float dist = sqrtf(fmaxf((disttot - pr[idx]) * pos, 0.f));
        float eff = __expf(gamma * dist);
        eff = fminf(fmaxf(eff, 1e-5f), 1e5f);
        sc[idx] = allowed ? sc[idx] * eff : -1e20f;
    }
    __syncthreads();

    // softmax #2
    mx = -1e30f;
    for (int idx = tid; idx < SS; idx += 256) mx = fmaxf(mx, sc[idx]);
    mx = block_reduce_max(mx, red, tid);
    sm = 0.f;
    for (int idx = tid; idx < SS; idx += 256) {
        float e = __expf(sc[idx] - mx);
        pr[idx] = e;
        sm += e;
    }
    sm = block_reduce_sum(sm, red, tid);
    const float inv2 = 1.f / sm;
    const bool zero = (mask == 0) && (i == 0);   // reference zero-pads row 0
    for (int idx = tid; idx < SS; idx += 256) pr[idx] = zero ? 0.f : pr[idx] * inv2;
    __syncthreads();

    // out[i, d] = sum_j attn[j] * V[j, d]; 4 quarters x 64 dims
    const int d = tid & 63, quar = tid >> 6;
    int lim = i + mask;                       // pr[j]==0 for j>=lim when lim>=1
    int jend = (lim >= 1 && lim < SS) ? lim : SS;
    int j0 = quar * 256;
    int j1 = min(j0 + 256, jend);
    float o = 0.f;
    for (int j = j0; j < j1; j++) o += pr[j] * V[basekv + (size_t)j * DDIM + d];
    redv[tid] = o;
    __syncthreads();
    if (tid < 64) {
        float r = redv[tid] + redv[64 + tid] + redv[128 + tid] + redv[192 + tid];
        out[(size_t)(b * SS + i) * DDIM + h * DKK + tid] = r;
    }
}

// ---------- fused residual-add + LayerNorm, one block per row ----------
__global__ __launch_bounds__(256) void add_ln(const float* __restrict__ R,
                                              const float* __restrict__ Y,
                                              const float* __restrict__ w,
                                              const float* __restrict__ bb,
                                              float* __restrict__ out) {
    const int row = blockIdx.x;
    const int tid = threadIdx.x;
    __shared__ float red[4];
    __shared__ float xs[DDIM];
    const size_t base = (size_t)row * DDIM;
    float s = 0.f, s2 = 0.f;
#pragma unroll
    for (int l = 0; l < 4; l++) {
        int idx = tid + l * 256;
        float x = R[base + idx] + Y[base + idx];
        xs[idx] = x;
        s += x;
        s2 += x * x;
    }
    s = block_reduce_sum(s, red, tid);
    s2 = block_reduce_sum(s2, red, tid);
    const float mu = s * (1.f / DDIM);
    const float var = s2 * (1.f / DDIM) - mu * mu;
    const float rstd = rsqrtf(var + 1e-5f);
#pragma unroll
    for (int l = 0; l < 4; l++) {
        int idx = tid + l * 256;
        float v = (xs[idx] - mu) * rstd * w[idx] + bb[idx];
        out[base + idx] = v;
    }
}

extern "C" void kernel_launch(void* const* d_in, const int* in_sizes, int n_in,
                              void* d_out, int out_size, void* d_ws, size_t ws_size,
                              hipStream_t stream) {
    const int*   maskp  = (const int*)d_in[0];
    const float* query  = (const float*)d_in[1];
    const float* key    = (const float*)d_in[2];
    const float* values = (const float*)d_in[3];
    const float* Wq = (const float*)d_in[4];
    const float* bq = (const float*)d_in[5];
    const float* Wk = (const float*)d_in[6];
    const float* bk = (const float*)d_in[7];
    const float* Wv = (const float*)d_in[8];
    const float* bv = (const float*)d_in[9];
    const float* Wo = (const float*)d_in[10];
    const float* bo = (const float*)d_in[11];
    const float* gammas = (const float*)d_in[12];
    const float* ln1w = (const float*)d_in[13];
    const float* ln1b = (const float*)d_in[14];
    const float* W1 = (const float*)d_in[15];
    const float* b1 = (const float*)d_in[16];
    const float* W2 = (const float*)d_in[17];
    const float* b2 = (const float*)d_in[18];
    const float* ln2w = (const float*)d_in[19];
    const float* ln2b = (const float*)d_in[20];

    const int M = BB * SS;                 // 4096 rows
    float* ws = (float*)d_ws;
    float* bQ   = ws;                      // 4M floats (16 MB)
    float* bK   = ws + (size_t)4194304;
    float* bV   = ws + (size_t)8388608;
    float* bATT = ws + (size_t)12582912;
    float* bFFN = ws + (size_t)16777216;   // 16M floats (64 MB)

    dim3 blk(256);

    // QKV projections: [4096,1024] = in @ W^T + b
    gemm_nt<false><<<dim3(16, 64), blk, 0, stream>>>(query,  Wq, bq, bQ, M, DDIM, DDIM);
    gemm_nt<false><<<dim3(16, 64), blk, 0, stream>>>(key,    Wk, bk, bK, M, DDIM, DDIM);
    gemm_nt<false><<<dim3(16, 64), blk, 0, stream>>>(values, Wv, bv, bV, M, DDIM, DDIM);

    // attention: one block per (b,h,i)
    attn_row<<<dim3(BB * HH * SS), blk, 0, stream>>>(bQ, bK, bV, gammas, maskp, bATT);

    // output projection -> bQ (Q dead)
    gemm_nt<false><<<dim3(16, 64), blk, 0, stream>>>(bATT, Wo, bo, bQ, M, DDIM, DDIM);

    // x = LN(query + attn_out) -> bK (K dead)
    add_ln<<<dim3(M), blk, 0, stream>>>(query, bQ, ln1w, ln1b, bK);

    // hidden = relu(x @ W1^T + b1) -> bFFN
    gemm_nt<true><<<dim3(64, 64), blk, 0, stream>>>(bK, W1, b1, bFFN, M, DFFF, DDIM);

    // y = hidden @ W2^T + b2 -> bQ
    gemm_nt<false><<<dim3(16, 64), blk, 0, stream>>>(bFFN, W2, b2, bQ, M, DDIM, DFFF);

    // out = LN(x + y) -> d_out (fp32)
    add_ln<<<dim3(M), blk, 0, stream>>>(bK, bQ, ln2w, ln2b, (float*)d_out);
}

// Round 3
// 3858.929 us; speedup vs baseline: 1.9083x; 1.9083x over previous
//
#include <hip/hip_runtime.h>
#include <hip/hip_bf16.h>
#include <math.h>

#define BB   4
#define SS   1024
#define DDIM 1024
#define HH   16
#define DKK  64
#define DFFF 4096
#define JC   128     // K/V j-chunk staged in LDS
#define TIB  16      // query rows per tile

// ---------- block reductions (256 threads = 4 waves of 64) ----------
__device__ __forceinline__ float block_reduce_sum(float v, float* red, int tid) {
#pragma unroll
    for (int off = 32; off; off >>= 1) v += __shfl_xor(v, off);
    __syncthreads();
    if ((tid & 63) == 0) red[tid >> 6] = v;
    __syncthreads();
    return red[0] + red[1] + red[2] + red[3];
}

// ---------- generic GEMM: C[M,N] = act(A[M,K] * W[N,K]^T + bias[N]) ----------
template <bool RELU>
__global__ __launch_bounds__(256) void gemm_nt(const float* __restrict__ A,
                                               const float* __restrict__ W,
                                               const float* __restrict__ bias,
                                               float* __restrict__ C,
                                               int M, int N, int K) {
    __shared__ float As[16][65];
    __shared__ float Ws[16][65];
    const int tid = threadIdx.x;
    const int tx = tid & 15, ty = tid >> 4;
    const int bm = blockIdx.y * 64, bn = blockIdx.x * 64;
    float acc[4][4] = {};

    for (int kt = 0; kt < K; kt += 16) {
#pragma unroll
        for (int l = 0; l < 4; l++) {
            int idx = tid * 4 + l;
            int k = idx & 15, m = idx >> 4;
            As[k][m] = A[(size_t)(bm + m) * K + kt + k];
            Ws[k][m] = W[(size_t)(bn + m) * K + kt + k];
        }
        __syncthreads();
#pragma unroll
        for (int k = 0; k < 16; k++) {
            float a[4], w[4];
#pragma unroll
            for (int u = 0; u < 4; u++) a[u] = As[k][ty + 16 * u];
#pragma unroll
            for (int v = 0; v < 4; v++) w[v] = Ws[k][tx + 16 * v];
#pragma unroll
            for (int u = 0; u < 4; u++)
#pragma unroll
                for (int v = 0; v < 4; v++) acc[u][v] += a[u] * w[v];
        }
        __syncthreads();
    }
#pragma unroll
    for (int u = 0; u < 4; u++) {
        int m = bm + ty + 16 * u;
#pragma unroll
        for (int v = 0; v < 4; v++) {
            int n = bn + tx + 16 * v;
            float r = acc[u][v] + bias[n];
            if (RELU) r = fmaxf(r, 0.f);
            C[(size_t)m * N + n] = r;
        }
    }
}

// ---------- tiled attention ----------
// 1024 blocks; block -> (b,h) slice, 4 sequential 16-row tiles.
// Per tile: scores -> global scratch Sg (L2-resident 64KB tile), row passes
// in registers with width-16 shuffle scans, PV from LDS-staged V chunks.
__global__ __launch_bounds__(256, 4) void attn_tiled(
    const float* __restrict__ Q, const float* __restrict__ Kg,
    const float* __restrict__ Vg, const float* __restrict__ gammas,
    const int* __restrict__ maskp, float* __restrict__ Sg,
    float* __restrict__ out) {
    __shared__ float KVs[JC * 68];     // K or V chunk, [j][d] stride 68 (pad)
    __shared__ float Qs[TIB * 68];     // Q tile, [i][d] stride 68
    __shared__ float rowmax_s[TIB];
    __shared__ float rowscale_s[TIB];

    const int t = threadIdx.x;
    const int bid = blockIdx.x;
    const int bh = bid >> 4;            // 0..63
    const int ig = bid & 15;            // 0..15 -> 4 tiles each
    const int b = bh >> 4;              // 0..3
    const int h = bh & 15;
    const int mask = *maskp;

    const float g0 = gammas[h];
    const float gamma = -((g0 > 20.f) ? g0 : log1pf(__expf(g0)));

    float* Sblk = Sg + (size_t)bid * (TIB * SS);
    const size_t kvbase = (size_t)b * SS * DDIM + (size_t)h * DKK;

    for (int tile = 0; tile < 4; ++tile) {
        const int i0 = (ig * 4 + tile) * TIB;

        // ---- stage Q tile [i][d] ----
        {
            int i = t >> 4, d4 = (t & 15) << 2;
            float4 v = *(const float4*)&Q[(size_t)(b * SS + i0 + i) * DDIM + h * DKK + d4];
            *(float4*)&Qs[i * 68 + d4] = v;
        }

        // ---- score phase: S = (Q K^T)/8 -> Sblk, track row maxima ----
        const int ti4 = (t >> 6) << 2;   // this wave's 4 rows
        const int tj = t & 63;
        float rmx0 = -3.4e38f, rmx1 = -3.4e38f, rmx2 = -3.4e38f, rmx3 = -3.4e38f;
        for (int ck = 0; ck < SS / JC; ++ck) {
            const int jc = ck * JC;
            __syncthreads();              // prev chunk compute / prev tile done
#pragma unroll
            for (int p = 0; p < 8; ++p) { // stage K chunk: 128x64 floats
                int f = p * 256 + t;
                int j = f >> 4, d4 = (f & 15) << 2;
                float4 v = *(const float4*)&Kg[kvbase + (size_t)(jc + j) * DDIM + d4];
                *(float4*)&KVs[j * 68 + d4] = v;
            }
            __syncthreads();
            float a00=0,a01=0,a10=0,a11=0,a20=0,a21=0,a30=0,a31=0;
#pragma unroll
            for (int d0 = 0; d0 < DKK; d0 += 4) {
                float4 q0 = *(const float4*)&Qs[(ti4 + 0) * 68 + d0];
                float4 q1 = *(const float4*)&Qs[(ti4 + 1) * 68 + d0];
                float4 q2 = *(const float4*)&Qs[(ti4 + 2) * 68 + d0];
                float4 q3 = *(const float4*)&Qs[(ti4 + 3) * 68 + d0];
                float4 k0 = *(const float4*)&KVs[tj * 68 + d0];
                float4 k1 = *(const float4*)&KVs[(tj + 64) * 68 + d0];
                a00 += q0.x*k0.x + q0.y*k0.y + q0.z*k0.z + q0.w*k0.w;
                a01 += q0.x*k1.x + q0.y*k1.y + q0.z*k1.z + q0.w*k1.w;
                a10 += q1.x*k0.x + q1.y*k0.y + q1.z*k0.z + q1.w*k0.w;
                a11 += q1.x*k1.x + q1.y*k1.y + q1.z*k1.z + q1.w*k1.w;
                a20 += q2.x*k0.x + q2.y*k0.y + q2.z*k0.z + q2.w*k0.w;
                a21 += q2.x*k1.x + q2.y*k1.y + q2.z*k1.z + q2.w*k1.w;
                a30 += q3.x*k0.x + q3.y*k0.y + q3.z*k0.z + q3.w*k0.w;
                a31 += q3.x*k1.x + q3.y*k1.y + q3.z*k1.z + q3.w*k1.w;
            }
            a00 *= 0.125f; a01 *= 0.125f; a10 *= 0.125f; a11 *= 0.125f;
            a20 *= 0.125f; a21 *= 0.125f; a30 *= 0.125f; a31 *= 0.125f;
            Sblk[(size_t)(ti4 + 0) * SS + jc + tj] = a00;
            Sblk[(size_t)(ti4 + 0) * SS + jc + tj + 64] = a01;
            Sblk[(size_t)(ti4 + 1) * SS + jc + tj] = a10;
            Sblk[(size_t)(ti4 + 1) * SS + jc + tj + 64] = a11;
            Sblk[(size_t)(ti4 + 2) * SS + jc + tj] = a20;
            Sblk[(size_t)(ti4 + 2) * SS + jc + tj + 64] = a21;
            Sblk[(size_t)(ti4 + 3) * SS + jc + tj] = a30;
            Sblk[(size_t)(ti4 + 3) * SS + jc + tj + 64] = a31;
            rmx0 = fmaxf(rmx0, fmaxf(a00, a01));
            rmx1 = fmaxf(rmx1, fmaxf(a10, a11));
            rmx2 = fmaxf(rmx2, fmaxf(a20, a21));
            rmx3 = fmaxf(rmx3, fmaxf(a30, a31));
        }
#pragma unroll
        for (int off = 1; off < 64; off <<= 1) {
            rmx0 = fmaxf(rmx0, __shfl_xor(rmx0, off));
            rmx1 = fmaxf(rmx1, __shfl_xor(rmx1, off));
            rmx2 = fmaxf(rmx2, __shfl_xor(rmx2, off));
            rmx3 = fmaxf(rmx3, __shfl_xor(rmx3, off));
        }
        if (tj == 0) {
            rowmax_s[ti4 + 0] = rmx0; rowmax_s[ti4 + 1] = rmx1;
            rowmax_s[ti4 + 2] = rmx2; rowmax_s[ti4 + 3] = rmx3;
        }
        __threadfence_block();   // make Sblk stores visible block-wide
        __syncthreads();

        // ---- row passes: thread (r,c) owns row r cols [64c, 64c+64) ----
        const int r = t >> 4, c = t & 15;
        const int gi = i0 + r;
        const int lim = gi + mask;        // allowed: j < lim
        const float mx = rowmax_s[r];
        float* Srow = Sblk + (size_t)r * SS;

        // p3: unmasked sum + masked chunk-sum
        float sumu = 0.f, msum = 0.f;
#pragma unroll
        for (int a = 0; a < 16; ++a) {
            int jb = (c << 6) + (a << 2);
            float4 v = *(const float4*)&Srow[jb];
            float e0 = __expf(v.x - mx), e1 = __expf(v.y - mx);
            float e2 = __expf(v.z - mx), e3 = __expf(v.w - mx);
            sumu += (e0 + e1) + (e2 + e3);
            msum += (jb + 0 < lim ? e0 : 0.f) + (jb + 1 < lim ? e1 : 0.f)
                  + (jb + 2 < lim ? e2 : 0.f) + (jb + 3 < lim ? e3 : 0.f);
        }
#pragma unroll
        for (int m2 = 1; m2 < 16; m2 <<= 1) sumu += __shfl_xor(sumu, m2, 16);
        float incl = msum;
#pragma unroll
        for (int dd = 1; dd < 16; dd <<= 1) {
            float tt = __shfl_up(incl, dd, 16);
            if (c >= dd) incl += tt;
        }
        float run = incl - msum;                    // exclusive prefix
        const float rowtot = __shfl(incl, 15, 16);  // masked row total (raw)
        const float inv = 1.f / sumu;

        // p4: distance-decay rescale + causal mask, track new row max
        float mx2 = -3.4e38f;
#pragma unroll
        for (int a = 0; a < 16; ++a) {
            int jb = (c << 6) + (a << 2);
            float4 v = *(const float4*)&Srow[jb];
            float4 o;
            {   int j = jb; bool al = j < lim;
                float e = al ? __expf(v.x - mx) : 0.f; run += e;
                float pos = fabsf((float)(j - gi));
                float d2 = fmaxf((rowtot - run) * inv * pos, 0.f);
                float eff = fminf(fmaxf(__expf(gamma * sqrtf(d2)), 1e-5f), 1e5f);
                o.x = al ? v.x * eff : -1e20f; }
            {   int j = jb + 1; bool al = j < lim;
                float e = al ? __expf(v.y - mx) : 0.f; run += e;
                float pos = fabsf((float)(j - gi));
                float d2 = fmaxf((rowtot - run) * inv * pos, 0.f);
                float eff = fminf(fmaxf(__expf(gamma * sqrtf(d2)), 1e-5f), 1e5f);
                o.y = al ? v.y * eff : -1e20f; }
            {   int j = jb + 2; bool al = j < lim;
                float e = al ? __expf(v.z - mx) : 0.f; run += e;
                float pos = fabsf((float)(j - gi));
                float d2 = fmaxf((rowtot - run) * inv * pos, 0.f);
                float eff = fminf(fmaxf(__expf(gamma * sqrtf(d2)), 1e-5f), 1e5f);
                o.z = al ? v.z * eff : -1e20f; }
            {   int j = jb + 3; bool al = j < lim;
                float e = al ? __expf(v.w - mx) : 0.f; run += e;
                float pos = fabsf((float)(j - gi));
                float d2 = fmaxf((rowtot - run) * inv * pos, 0.f);
                float eff = fminf(fmaxf(__expf(gamma * sqrtf(d2)), 1e-5f), 1e5f);
                o.w = al ? v.w * eff : -1e20f; }
            mx2 = fmaxf(mx2, fmaxf(fmaxf(o.x, o.y), fmaxf(o.z, o.w)));
            *(float4*)&Srow[jb] = o;
        }
#pragma unroll
        for (int m2 = 1; m2 < 16; m2 <<= 1) mx2 = fmaxf(mx2, __shfl_xor(mx2, m2, 16));
        __threadfence_block();   // own stores through L1 before re-read

        // p5: softmax#2 numerator, write P (unnormalized); scale at PV output
        float sm2 = 0.f;
#pragma unroll
        for (int a = 0; a < 16; ++a) {
            int jb = (c << 6) + (a << 2);
            float4 v = *(const float4*)&Srow[jb];
            float4 e;
            e.x = __expf(v.x - mx2); e.y = __expf(v.y - mx2);
            e.z = __expf(v.z - mx2); e.w = __expf(v.w - mx2);
            sm2 += (e.x + e.y) + (e.z + e.w);
            *(float4*)&Srow[jb] = e;
        }
#pragma unroll
        for (int m2 = 1; m2 < 16; m2 <<= 1) sm2 += __shfl_xor(sm2, m2, 16);
        if (c == 0) {
            float sc = 1.f / sm2;
            if (mask == 0 && gi == 0) sc = 0.f;   // reference zero-pads row 0
            rowscale_s[r] = sc;
        }
        __threadfence_block();

        // ---- PV: out[i][d] = rowscale[i] * sum_j P[i][j] V[j][d] ----
        const int pi = t >> 4;              // row 0..15
        const int d0 = (t & 15) << 2;       // 4 d per thread
        float o0 = 0.f, o1 = 0.f, o2 = 0.f, o3 = 0.f;
        const float* Prow = Sblk + (size_t)pi * SS;
        for (int cv = 0; cv < SS / JC; ++cv) {
            const int jc = cv * JC;
            __syncthreads();                 // P stores visible; KVs reusable
#pragma unroll
            for (int p = 0; p < 8; ++p) {    // stage V chunk
                int f = p * 256 + t;
                int j = f >> 4, d4 = (f & 15) << 2;
                float4 v = *(const float4*)&Vg[kvbase + (size_t)(jc + j) * DDIM + d4];
                *(float4*)&KVs[j * 68 + d4] = v;
            }
            __syncthreads();
#pragma unroll 4
            for (int j4 = 0; j4 < JC; j4 += 4) {
                float4 pp = *(const float4*)&Prow[jc + j4];
                float4 v0 = *(const float4*)&KVs[(j4 + 0) * 68 + d0];
                float4 v1 = *(const float4*)&KVs[(j4 + 1) * 68 + d0];
                float4 v2 = *(const float4*)&KVs[(j4 + 2) * 68 + d0];
                float4 v3 = *(const float4*)&KVs[(j4 + 3) * 68 + d0];
                o0 += pp.x*v0.x + pp.y*v1.x + pp.z*v2.x + pp.w*v3.x;
                o1 += pp.x*v0.y + pp.y*v1.y + pp.z*v2.y + pp.w*v3.y;
                o2 += pp.x*v0.z + pp.y*v1.z + pp.z*v2.z + pp.w*v3.z;
                o3 += pp.x*v0.w + pp.y*v1.w + pp.z*v2.w + pp.w*v3.w;
            }
        }
        const float scl = rowscale_s[pi];
        float4 res;
        res.x = o0 * scl; res.y = o1 * scl; res.z = o2 * scl; res.w = o3 * scl;
        *(float4*)&out[(size_t)(b * SS + i0 + pi) * DDIM + h * DKK + d0] = res;
        __syncthreads();   // tile boundary: Qs/KVs/rowscale reuse
    }
}

// ---------- fused residual-add + LayerNorm, one block per row ----------
__global__ __launch_bounds__(256) void add_ln(const float* __restrict__ R,
                                              const float* __restrict__ Y,
                                              const float* __restrict__ w,
                                              const float* __restrict__ bb,
                                              float* __restrict__ out) {
    const int row = blockIdx.x;
    const int tid = threadIdx.x;
    __shared__ float red[4];
    __shared__ float xs[DDIM];
    const size_t base = (size_t)row * DDIM;
    float s = 0.f, s2 = 0.f;
#pragma unroll
    for (int l = 0; l < 4; l++) {
        int idx = tid + l * 256;
        float x = R[base + idx] + Y[base + idx];
        xs[idx] = x;
        s += x;
        s2 += x * x;
    }
    s = block_reduce_sum(s, red, tid);
    s2 = block_reduce_sum(s2, red, tid);
    const float mu = s * (1.f / DDIM);
    const float var = s2 * (1.f / DDIM) - mu * mu;
    const float rstd = rsqrtf(var + 1e-5f);
#pragma unroll
    for (int l = 0; l < 4; l++) {
        int idx = tid + l * 256;
        out[base + idx] = (xs[idx] - mu) * rstd * w[idx] + bb[idx];
    }
}

extern "C" void kernel_launch(void* const* d_in, const int* in_sizes, int n_in,
                              void* d_out, int out_size, void* d_ws, size_t ws_size,
                              hipStream_t stream) {
    const int*   maskp  = (const int*)d_in[0];
    const float* query  = (const float*)d_in[1];
    const float* key    = (const float*)d_in[2];
    const float* values = (const float*)d_in[3];
    const float* Wq = (const float*)d_in[4];
    const float* bq = (const float*)d_in[5];
    const float* Wk = (const float*)d_in[6];
    const float* bk = (const float*)d_in[7];
    const float* Wv = (const float*)d_in[8];
    const float* bv = (const float*)d_in[9];
    const float* Wo = (const float*)d_in[10];
    const float* bo = (const float*)d_in[11];
    const float* gammas = (const float*)d_in[12];
    const float* ln1w = (const float*)d_in[13];
    const float* ln1b = (const float*)d_in[14];
    const float* W1 = (const float*)d_in[15];
    const float* b1 = (const float*)d_in[16];
    const float* W2 = (const float*)d_in[17];
    const float* b2 = (const float*)d_in[18];
    const float* ln2w = (const float*)d_in[19];
    const float* ln2b = (const float*)d_in[20];

    const int M = BB * SS;                 // 4096 rows
    float* ws = (float*)d_ws;
    float* bQ   = ws;                      // 4M floats (16 MB)
    float* bK   = ws + (size_t)4194304;
    float* bV   = ws + (size_t)8388608;
    float* bATT = ws + (size_t)12582912;
    float* bFFN = ws + (size_t)16777216;   // 16M floats (64 MB); doubles as
                                           // attention score scratch (time-disjoint)
    dim3 blk(256);

    // QKV projections: [4096,1024] = in @ W^T + b
    gemm_nt<false><<<dim3(16, 64), blk, 0, stream>>>(query,  Wq, bq, bQ, M, DDIM, DDIM);
    gemm_nt<false><<<dim3(16, 64), blk, 0, stream>>>(key,    Wk, bk, bK, M, DDIM, DDIM);
    gemm_nt<false><<<dim3(16, 64), blk, 0, stream>>>(values, Wv, bv, bV, M, DDIM, DDIM);

    // attention (tiled, score scratch aliases bFFN)
    attn_tiled<<<dim3(1024), blk, 0, stream>>>(bQ, bK, bV, gammas, maskp, bFFN, bATT);

    // output projection -> bQ (Q dead)
    gemm_nt<false><<<dim3(16, 64), blk, 0, stream>>>(bATT, Wo, bo, bQ, M, DDIM, DDIM);

    // x = LN(query + attn_out) -> bK (K dead)
    add_ln<<<dim3(M), blk, 0, stream>>>(query, bQ, ln1w, ln1b, bK);

    // hidden = relu(x @ W1^T + b1) -> bFFN
    gemm_nt<true><<<dim3(64, 64), blk, 0, stream>>>(bK, W1, b1, bFFN, M, DFFF, DDIM);

    // y = hidden @ W2^T + b2 -> bQ
    gemm_nt<false><<<dim3(16, 64), blk, 0, stream>>>(bFFN, W2, b2, bQ, M, DDIM, DFFF);

    // out = LN(x + y) -> d_out (fp32)
    add_ln<<<dim3(M), blk, 0, stream>>>(bK, bQ, ln2w, ln2b, (float*)d_out);
}

// Round 4
// 2536.084 us; speedup vs baseline: 2.9036x; 1.5216x over previous
//
#include <hip/hip_runtime.h>
#include <hip/hip_bf16.h>
#include <math.h>

#define BB   4
#define SS   1024
#define DDIM 1024
#define HH   16
#define DKK  64
#define DFFF 4096
#define JC   128     // K/V j-chunk staged in LDS (attention)
#define TIB  16      // query rows per tile (attention)

typedef __attribute__((ext_vector_type(8))) short short8;
typedef __attribute__((ext_vector_type(4))) float f32x4;

__device__ __forceinline__ unsigned short f2bf(float f) {   // RNE fp32->bf16
    unsigned int u = __float_as_uint(f);
    unsigned int r = (u + 0x7FFFu + ((u >> 16) & 1u)) >> 16;
    return (unsigned short)r;
}

// ---------- block reductions (256 threads = 4 waves of 64) ----------
__device__ __forceinline__ float block_reduce_sum(float v, float* red, int tid) {
#pragma unroll
    for (int off = 32; off; off >>= 1) v += __shfl_xor(v, off);
    __syncthreads();
    if ((tid & 63) == 0) red[tid >> 6] = v;
    __syncthreads();
    return red[0] + red[1] + red[2] + red[3];
}

// ---------- bf16 MFMA GEMM: C[M,N] = act(A[M,K] @ W[N,K]^T + bias[N]) ----------
// 128x128 tile, BK=32, 256 threads / 4 waves, wave = 64x64 (4x4 MFMA 16x16x32).
// A: fp32 or bf16(ushort); W,bias fp32; C: fp32 or bf16(ushort). fp32 accum.
// LDS row stride 56 shorts (112 B): 16B-aligned b128, 2-way banks (free).
template <typename TA, typename TC, bool RELU>
__global__ __launch_bounds__(256, 2) void gemm_mfma(const TA* __restrict__ A,
                                                    const float* __restrict__ W,
                                                    const float* __restrict__ bias,
                                                    TC* __restrict__ C,
                                                    int M, int N, int K) {
    __shared__ short A_s[128 * 56];
    __shared__ short B_s[128 * 56];
    const int t = threadIdx.x;
    const int bm = blockIdx.y * 128, bn = blockIdx.x * 128;
    const int lane = t & 63, w = t >> 6;
    const int wr = w >> 1, wc = w & 1;          // wave sub-tile origin /64
    const int fm = lane & 15, fq = lane >> 4;   // fragment row, k-quad

    const int sr = t >> 1;                       // staging row 0..127
    const int sh = (t & 1) << 4;                 // staging col 0 / 16

    f32x4 acc[4][4];
#pragma unroll
    for (int i = 0; i < 4; i++)
#pragma unroll
        for (int j = 0; j < 4; j++) acc[i][j] = (f32x4){0.f, 0.f, 0.f, 0.f};

    for (int kt = 0; kt < K; kt += 32) {
        __syncthreads();
        // ---- stage A (128x32) ----
        if constexpr (sizeof(TA) == 4) {
            const float* ga = (const float*)A + (size_t)(bm + sr) * K + kt + sh;
            float4 f0 = *(const float4*)(ga);
            float4 f1 = *(const float4*)(ga + 4);
            float4 f2 = *(const float4*)(ga + 8);
            float4 f3 = *(const float4*)(ga + 12);
            short8 s0, s1;
            s0[0] = (short)f2bf(f0.x); s0[1] = (short)f2bf(f0.y);
            s0[2] = (short)f2bf(f0.z); s0[3] = (short)f2bf(f0.w);
            s0[4] = (short)f2bf(f1.x); s0[5] = (short)f2bf(f1.y);
            s0[6] = (short)f2bf(f1.z); s0[7] = (short)f2bf(f1.w);
            s1[0] = (short)f2bf(f2.x); s1[1] = (short)f2bf(f2.y);
            s1[2] = (short)f2bf(f2.z); s1[3] = (short)f2bf(f2.w);
            s1[4] = (short)f2bf(f3.x); s1[5] = (short)f2bf(f3.y);
            s1[6] = (short)f2bf(f3.z); s1[7] = (short)f2bf(f3.w);
            *(short8*)&A_s[sr * 56 + sh] = s0;
            *(short8*)&A_s[sr * 56 + sh + 8] = s1;
        } else {
            const unsigned short* ga = (const unsigned short*)A + (size_t)(bm + sr) * K + kt + sh;
            *(short8*)&A_s[sr * 56 + sh]     = *(const short8*)(ga);
            *(short8*)&A_s[sr * 56 + sh + 8] = *(const short8*)(ga + 8);
        }
        // ---- stage B = W rows (128x32) ----
        {
            const float* gb = W + (size_t)(bn + sr) * K + kt + sh;
            float4 f0 = *(const float4*)(gb);
            float4 f1 = *(const float4*)(gb + 4);
            float4 f2 = *(const float4*)(gb + 8);
            float4 f3 = *(const float4*)(gb + 12);
            short8 s0, s1;
            s0[0] = (short)f2bf(f0.x); s0[1] = (short)f2bf(f0.y);
            s0[2] = (short)f2bf(f0.z); s0[3] = (short)f2bf(f0.w);
            s0[4] = (short)f2bf(f1.x); s0[5] = (short)f2bf(f1.y);
            s0[6] = (short)f2bf(f1.z); s0[7] = (short)f2bf(f1.w);
            s1[0] = (short)f2bf(f2.x); s1[1] = (short)f2bf(f2.y);
            s1[2] = (short)f2bf(f2.z); s1[3] = (short)f2bf(f2.w);
            s1[4] = (short)f2bf(f3.x); s1[5] = (short)f2bf(f3.y);
            s1[6] = (short)f2bf(f3.z); s1[7] = (short)f2bf(f3.w);
            *(short8*)&B_s[sr * 56 + sh] = s0;
            *(short8*)&B_s[sr * 56 + sh + 8] = s1;
        }
        __syncthreads();
        // ---- compute: 16 MFMA per wave ----
        short8 av[4], bv[4];
#pragma unroll
        for (int mt = 0; mt < 4; mt++)
            av[mt] = *(const short8*)&A_s[(wr * 64 + mt * 16 + fm) * 56 + fq * 8];
#pragma unroll
        for (int nt = 0; nt < 4; nt++)
            bv[nt] = *(const short8*)&B_s[(wc * 64 + nt * 16 + fm) * 56 + fq * 8];
#pragma unroll
        for (int mt = 0; mt < 4; mt++)
#pragma unroll
            for (int nt = 0; nt < 4; nt++)
                acc[mt][nt] = __builtin_amdgcn_mfma_f32_16x16x32_bf16(
                    av[mt], bv[nt], acc[mt][nt], 0, 0, 0);
    }

    // ---- epilogue: D row = fq*4+reg, col = fm ----
#pragma unroll
    for (int mt = 0; mt < 4; mt++) {
        int row0 = bm + wr * 64 + mt * 16 + fq * 4;
#pragma unroll
        for (int nt = 0; nt < 4; nt++) {
            int col = bn + wc * 64 + nt * 16 + fm;
            float bsv = bias[col];
#pragma unroll
            for (int r = 0; r < 4; r++) {
                float val = acc[mt][nt][r] + bsv;
                if (RELU) val = fmaxf(val, 0.f);
                if constexpr (sizeof(TC) == 4)
                    ((float*)C)[(size_t)(row0 + r) * N + col] = val;
                else
                    ((unsigned short*)C)[(size_t)(row0 + r) * N + col] = f2bf(val);
            }
        }
    }
}

// ---------- tiled attention (unchanged from round 3) ----------
__global__ __launch_bounds__(256, 4) void attn_tiled(
    const float* __restrict__ Q, const float* __restrict__ Kg,
    const float* __restrict__ Vg, const float* __restrict__ gammas,
    const int* __restrict__ maskp, float* __restrict__ Sg,
    float* __restrict__ out) {
    __shared__ float KVs[JC * 68];
    __shared__ float Qs[TIB * 68];
    __shared__ float rowmax_s[TIB];
    __shared__ float rowscale_s[TIB];

    const int t = threadIdx.x;
    const int bid = blockIdx.x;
    const int bh = bid >> 4;
    const int ig = bid & 15;
    const int b = bh >> 4;
    const int h = bh & 15;
    const int mask = *maskp;

    const float g0 = gammas[h];
    const float gamma = -((g0 > 20.f) ? g0 : log1pf(__expf(g0)));

    float* Sblk = Sg + (size_t)bid * (TIB * SS);
    const size_t kvbase = (size_t)b * SS * DDIM + (size_t)h * DKK;

    for (int tile = 0; tile < 4; ++tile) {
        const int i0 = (ig * 4 + tile) * TIB;
        {
            int i = t >> 4, d4 = (t & 15) << 2;
            float4 v = *(const float4*)&Q[(size_t)(b * SS + i0 + i) * DDIM + h * DKK + d4];
            *(float4*)&Qs[i * 68 + d4] = v;
        }
        const int ti4 = (t >> 6) << 2;
        const int tj = t & 63;
        float rmx0 = -3.4e38f, rmx1 = -3.4e38f, rmx2 = -3.4e38f, rmx3 = -3.4e38f;
        for (int ck = 0; ck < SS / JC; ++ck) {
            const int jc = ck * JC;
            __syncthreads();
#pragma unroll
            for (int p = 0; p < 8; ++p) {
                int f = p * 256 + t;
                int j = f >> 4, d4 = (f & 15) << 2;
                float4 v = *(const float4*)&Kg[kvbase + (size_t)(jc + j) * DDIM + d4];
                *(float4*)&KVs[j * 68 + d4] = v;
            }
            __syncthreads();
            float a00=0,a01=0,a10=0,a11=0,a20=0,a21=0,a30=0,a31=0;
#pragma unroll
            for (int d0 = 0; d0 < DKK; d0 += 4) {
                float4 q0 = *(const float4*)&Qs[(ti4 + 0) * 68 + d0];
                float4 q1 = *(const float4*)&Qs[(ti4 + 1) * 68 + d0];
                float4 q2 = *(const float4*)&Qs[(ti4 + 2) * 68 + d0];
                float4 q3 = *(const float4*)&Qs[(ti4 + 3) * 68 + d0];
                float4 k0 = *(const float4*)&KVs[tj * 68 + d0];
                float4 k1 = *(const float4*)&KVs[(tj + 64) * 68 + d0];
                a00 += q0.x*k0.x + q0.y*k0.y + q0.z*k0.z + q0.w*k0.w;
                a01 += q0.x*k1.x + q0.y*k1.y + q0.z*k1.z + q0.w*k1.w;
                a10 += q1.x*k0.x + q1.y*k0.y + q1.z*k0.z + q1.w*k0.w;
                a11 += q1.x*k1.x + q1.y*k1.y + q1.z*k1.z + q1.w*k1.w;
                a20 += q2.x*k0.x + q2.y*k0.y + q2.z*k0.z + q2.w*k0.w;
                a21 += q2.x*k1.x + q2.y*k1.y + q2.z*k1.z + q2.w*k1.w;
                a30 += q3.x*k0.x + q3.y*k0.y + q3.z*k0.z + q3.w*k0.w;
                a31 += q3.x*k1.x + q3.y*k1.y + q3.z*k1.z + q3.w*k1.w;
            }
            a00 *= 0.125f; a01 *= 0.125f; a10 *= 0.125f; a11 *= 0.125f;
            a20 *= 0.125f; a21 *= 0.125f; a30 *= 0.125f; a31 *= 0.125f;
            Sblk[(size_t)(ti4 + 0) * SS + jc + tj] = a00;
            Sblk[(size_t)(ti4 + 0) * SS + jc + tj + 64] = a01;
            Sblk[(size_t)(ti4 + 1) * SS + jc + tj] = a10;
            Sblk[(size_t)(ti4 + 1) * SS + jc + tj + 64] = a11;
            Sblk[(size_t)(ti4 + 2) * SS + jc + tj] = a20;
            Sblk[(size_t)(ti4 + 2) * SS + jc + tj + 64] = a21;
            Sblk[(size_t)(ti4 + 3) * SS + jc + tj] = a30;
            Sblk[(size_t)(ti4 + 3) * SS + jc + tj + 64] = a31;
            rmx0 = fmaxf(rmx0, fmaxf(a00, a01));
            rmx1 = fmaxf(rmx1, fmaxf(a10, a11));
            rmx2 = fmaxf(rmx2, fmaxf(a20, a21));
            rmx3 = fmaxf(rmx3, fmaxf(a30, a31));
        }
#pragma unroll
        for (int off = 1; off < 64; off <<= 1) {
            rmx0 = fmaxf(rmx0, __shfl_xor(rmx0, off));
            rmx1 = fmaxf(rmx1, __shfl_xor(rmx1, off));
            rmx2 = fmaxf(rmx2, __shfl_xor(rmx2, off));
            rmx3 = fmaxf(rmx3, __shfl_xor(rmx3, off));
        }
        if (tj == 0) {
            rowmax_s[ti4 + 0] = rmx0; rowmax_s[ti4 + 1] = rmx1;
            rowmax_s[ti4 + 2] = rmx2; rowmax_s[ti4 + 3] = rmx3;
        }
        __threadfence_block();
        __syncthreads();

        const int r = t >> 4, c = t & 15;
        const int gi = i0 + r;
        const int lim = gi + mask;
        const float mx = rowmax_s[r];
        float* Srow = Sblk + (size_t)r * SS;

        float sumu = 0.f, msum = 0.f;
#pragma unroll
        for (int a = 0; a < 16; ++a) {
            int jb = (c << 6) + (a << 2);
            float4 v = *(const float4*)&Srow[jb];
            float e0 = __expf(v.x - mx), e1 = __expf(v.y - mx);
            float e2 = __expf(v.z - mx), e3 = __expf(v.w - mx);
            sumu += (e0 + e1) + (e2 + e3);
            msum += (jb + 0 < lim ? e0 : 0.f) + (jb + 1 < lim ? e1 : 0.f)
                  + (jb + 2 < lim ? e2 : 0.f) + (jb + 3 < lim ? e3 : 0.f);
        }
#pragma unroll
        for (int m2 = 1; m2 < 16; m2 <<= 1) sumu += __shfl_xor(sumu, m2, 16);
        float incl = msum;
#pragma unroll
        for (int dd = 1; dd < 16; dd <<= 1) {
            float tt = __shfl_up(incl, dd, 16);
            if (c >= dd) incl += tt;
        }
        float run = incl - msum;
        const float rowtot = __shfl(incl, 15, 16);
        const float inv = 1.f / sumu;

        float mx2 = -3.4e38f;
#pragma unroll
        for (int a = 0; a < 16; ++a) {
            int jb = (c << 6) + (a << 2);
            float4 v = *(const float4*)&Srow[jb];
            float4 o;
            {   int j = jb; bool al = j < lim;
                float e = al ? __expf(v.x - mx) : 0.f; run += e;
                float pos = fabsf((float)(j - gi));
                float d2 = fmaxf((rowtot - run) * inv * pos, 0.f);
                float eff = fminf(fmaxf(__expf(gamma * sqrtf(d2)), 1e-5f), 1e5f);
                o.x = al ? v.x * eff : -1e20f; }
            {   int j = jb + 1; bool al = j < lim;
                float e = al ? __expf(v.y - mx) : 0.f; run += e;
                float pos = fabsf((float)(j - gi));
                float d2 = fmaxf((rowtot - run) * inv * pos, 0.f);
                float eff = fminf(fmaxf(__expf(gamma * sqrtf(d2)), 1e-5f), 1e5f);
                o.y = al ? v.y * eff : -1e20f; }
            {   int j = jb + 2; bool al = j < lim;
                float e = al ? __expf(v.z - mx) : 0.f; run += e;
                float pos = fabsf((float)(j - gi));
                float d2 = fmaxf((rowtot - run) * inv * pos, 0.f);
                float eff = fminf(fmaxf(__expf(gamma * sqrtf(d2)), 1e-5f), 1e5f);
                o.z = al ? v.z * eff : -1e20f; }
            {   int j = jb + 3; bool al = j < lim;
                float e = al ? __expf(v.w - mx) : 0.f; run += e;
                float pos = fabsf((float)(j - gi));
                float d2 = fmaxf((rowtot - run) * inv * pos, 0.f);
                float eff = fminf(fmaxf(__expf(gamma * sqrtf(d2)), 1e-5f), 1e5f);
                o.w = al ? v.w * eff : -1e20f; }
            mx2 = fmaxf(mx2, fmaxf(fmaxf(o.x, o.y), fmaxf(o.z, o.w)));
            *(float4*)&Srow[jb] = o;
        }
#pragma unroll
        for (int m2 = 1; m2 < 16; m2 <<= 1) mx2 = fmaxf(mx2, __shfl_xor(mx2, m2, 16));
        __threadfence_block();

        float sm2 = 0.f;
#pragma unroll
        for (int a = 0; a < 16; ++a) {
            int jb = (c << 6) + (a << 2);
            float4 v = *(const float4*)&Srow[jb];
            float4 e;
            e.x = __expf(v.x - mx2); e.y = __expf(v.y - mx2);
            e.z = __expf(v.z - mx2); e.w = __expf(v.w - mx2);
            sm2 += (e.x + e.y) + (e.z + e.w);
            *(float4*)&Srow[jb] = e;
        }
#pragma unroll
        for (int m2 = 1; m2 < 16; m2 <<= 1) sm2 += __shfl_xor(sm2, m2, 16);
        if (c == 0) {
            float sc = 1.f / sm2;
            if (mask == 0 && gi == 0) sc = 0.f;
            rowscale_s[r] = sc;
        }
        __threadfence_block();

        const int pi = t >> 4;
        const int d0 = (t & 15) << 2;
        float o0 = 0.f, o1 = 0.f, o2 = 0.f, o3 = 0.f;
        const float* Prow = Sblk + (size_t)pi * SS;
        for (int cv = 0; cv < SS / JC; ++cv) {
            const int jc = cv * JC;
            __syncthreads();
#pragma unroll
            for (int p = 0; p < 8; ++p) {
                int f = p * 256 + t;
                int j = f >> 4, d4 = (f & 15) << 2;
                float4 v = *(const float4*)&Vg[kvbase + (size_t)(jc + j) * DDIM + d4];
                *(float4*)&KVs[j * 68 + d4] = v;
            }
            __syncthreads();
#pragma unroll 4
            for (int j4 = 0; j4 < JC; j4 += 4) {
                float4 pp = *(const float4*)&Prow[jc + j4];
                float4 v0 = *(const float4*)&KVs[(j4 + 0) * 68 + d0];
                float4 v1 = *(const float4*)&KVs[(j4 + 1) * 68 + d0];
                float4 v2 = *(const float4*)&KVs[(j4 + 2) * 68 + d0];
                float4 v3 = *(const float4*)&KVs[(j4 + 3) * 68 + d0];
                o0 += pp.x*v0.x + pp.y*v1.x + pp.z*v2.x + pp.w*v3.x;
                o1 += pp.x*v0.y + pp.y*v1.y + pp.z*v2.y + pp.w*v3.y;
                o2 += pp.x*v0.z + pp.y*v1.z + pp.z*v2.z + pp.w*v3.z;
                o3 += pp.x*v0.w + pp.y*v1.w + pp.z*v2.w + pp.w*v3.w;
            }
        }
        const float scl = rowscale_s[pi];
        float4 res;
        res.x = o0 * scl; res.y = o1 * scl; res.z = o2 * scl; res.w = o3 * scl;
        *(float4*)&out[(size_t)(b * SS + i0 + pi) * DDIM + h * DKK + d0] = res;
        __syncthreads();
    }
}

// ---------- fused residual-add + LayerNorm (+ optional bf16 copy) ----------
template <bool WB>
__global__ __launch_bounds__(256) void add_ln(const float* __restrict__ R,
                                              const float* __restrict__ Y,
                                              const float* __restrict__ w,
                                              const float* __restrict__ bb,
                                              float* __restrict__ out,
                                              unsigned short* __restrict__ obf) {
    const int row = blockIdx.x;
    const int tid = threadIdx.x;
    __shared__ float red[4];
    __shared__ float xs[DDIM];
    const size_t base = (size_t)row * DDIM;
    float s = 0.f, s2 = 0.f;
#pragma unroll
    for (int l = 0; l < 4; l++) {
        int idx = tid + l * 256;
        float x = R[base + idx] + Y[base + idx];
        xs[idx] = x;
        s += x;
        s2 += x * x;
    }
    s = block_reduce_sum(s, red, tid);
    s2 = block_reduce_sum(s2, red, tid);
    const float mu = s * (1.f / DDIM);
    const float var = s2 * (1.f / DDIM) - mu * mu;
    const float rstd = rsqrtf(var + 1e-5f);
#pragma unroll
    for (int l = 0; l < 4; l++) {
        int idx = tid + l * 256;
        float v = (xs[idx] - mu) * rstd * w[idx] + bb[idx];
        out[base + idx] = v;
        if (WB) obf[base + idx] = f2bf(v);
    }
}

extern "C" void kernel_launch(void* const* d_in, const int* in_sizes, int n_in,
                              void* d_out, int out_size, void* d_ws, size_t ws_size,
                              hipStream_t stream) {
    const int*   maskp  = (const int*)d_in[0];
    const float* query  = (const float*)d_in[1];
    const float* key    = (const float*)d_in[2];
    const float* values = (const float*)d_in[3];
    const float* Wq = (const float*)d_in[4];
    const float* bq = (const float*)d_in[5];
    const float* Wk = (const float*)d_in[6];
    const float* bk = (const float*)d_in[7];
    const float* Wv = (const float*)d_in[8];
    const float* bv = (const float*)d_in[9];
    const float* Wo = (const float*)d_in[10];
    const float* bo = (const float*)d_in[11];
    const float* gammas = (const float*)d_in[12];
    const float* ln1w = (const float*)d_in[13];
    const float* ln1b = (const float*)d_in[14];
    const float* W1 = (const float*)d_in[15];
    const float* b1 = (const float*)d_in[16];
    const float* W2 = (const float*)d_in[17];
    const float* b2 = (const float*)d_in[18];
    const float* ln2w = (const float*)d_in[19];
    const float* ln2b = (const float*)d_in[20];

    const int M = BB * SS;                 // 4096 rows
    float* ws = (float*)d_ws;
    float* bQ   = ws;                               // 16 MB fp32
    float* bK   = ws + (size_t)4194304;             // 16 MB
    float* bV   = ws + (size_t)8388608;             // 16 MB
    float* bATT = ws + (size_t)12582912;            // 16 MB
    float* Sg   = ws + (size_t)16777216;            // 64 MB: attn score scratch
    // time-disjoint aliases of the Sg region (used only after attention):
    unsigned short* hidden = (unsigned short*)(ws + (size_t)16777216);            // 32 MB bf16
    unsigned short* x_bf   = (unsigned short*)(ws + (size_t)16777216 + 8388608);  // 8 MB bf16

    dim3 blk(256);

    // QKV projections (bf16 MFMA): [4096,1024] = in @ W^T + b
    gemm_mfma<float, float, false><<<dim3(8, 32), blk, 0, stream>>>(query,  Wq, bq, bQ, M, DDIM, DDIM);
    gemm_mfma<float, float, false><<<dim3(8, 32), blk, 0, stream>>>(key,    Wk, bk, bK, M, DDIM, DDIM);
    gemm_mfma<float, float, false><<<dim3(8, 32), blk, 0, stream>>>(values, Wv, bv, bV, M, DDIM, DDIM);

    // attention (tiled, score scratch in Sg)
    attn_tiled<<<dim3(1024), blk, 0, stream>>>(bQ, bK, bV, gammas, maskp, Sg, bATT);

    // output projection -> bQ (Q dead)
    gemm_mfma<float, float, false><<<dim3(8, 32), blk, 0, stream>>>(bATT, Wo, bo, bQ, M, DDIM, DDIM);

    // x = LN(query + attn_out) -> bK fp32 + x_bf bf16
    add_ln<true><<<dim3(M), blk, 0, stream>>>(query, bQ, ln1w, ln1b, bK, x_bf);

    // hidden = relu(x @ W1^T + b1) -> bf16
    gemm_mfma<unsigned short, unsigned short, true><<<dim3(32, 32), blk, 0, stream>>>(x_bf, W1, b1, hidden, M, DFFF, DDIM);

    // y = hidden @ W2^T + b2 -> bQ fp32
    gemm_mfma<unsigned short, float, false><<<dim3(8, 32), blk, 0, stream>>>(hidden, W2, b2, bQ, M, DDIM, DFFF);

    // out = LN(x + y) -> d_out (fp32)
    add_ln<false><<<dim3(M), blk, 0, stream>>>(bK, bQ, ln2w, ln2b, (float*)d_out, nullptr);
}

// Round 5
// 890.162 us; speedup vs baseline: 8.2725x; 2.8490x over previous
//
#include <hip/hip_runtime.h>
#include <hip/hip_bf16.h>
#include <math.h>

#define BB   4
#define SS   1024
#define DDIM 1024
#define HH   16
#define DKK  64
#define DFFF 4096
#define JC2  128     // K/V j-chunk per LDS stage (attention)

typedef __attribute__((ext_vector_type(8))) short short8;
typedef __attribute__((ext_vector_type(4))) float f32x4;

__device__ __forceinline__ unsigned short f2bf(float f) {   // RNE fp32->bf16
    unsigned int u = __float_as_uint(f);
    unsigned int r = (u + 0x7FFFu + ((u >> 16) & 1u)) >> 16;
    return (unsigned short)r;
}
__device__ __forceinline__ short8 pack8(float4 f0, float4 f1) {
    short8 s;
    s[0] = (short)f2bf(f0.x); s[1] = (short)f2bf(f0.y);
    s[2] = (short)f2bf(f0.z); s[3] = (short)f2bf(f0.w);
    s[4] = (short)f2bf(f1.x); s[5] = (short)f2bf(f1.y);
    s[6] = (short)f2bf(f1.z); s[7] = (short)f2bf(f1.w);
    return s;
}

// ---------- block reductions (256 threads = 4 waves of 64) ----------
__device__ __forceinline__ float block_reduce_sum(float v, float* red, int tid) {
#pragma unroll
    for (int off = 32; off; off >>= 1) v += __shfl_xor(v, off);
    __syncthreads();
    if ((tid & 63) == 0) red[tid >> 6] = v;
    __syncthreads();
    return red[0] + red[1] + red[2] + red[3];
}

// ---------- bf16 MFMA GEMM: C[M,N] = act(A[M,K] @ W[N,K]^T + bias[N]) ----------
// (unchanged from round 4 — verified)
template <typename TA, typename TC, bool RELU>
__global__ __launch_bounds__(256, 2) void gemm_mfma(const TA* __restrict__ A,
                                                    const float* __restrict__ W,
                                                    const float* __restrict__ bias,
                                                    TC* __restrict__ C,
                                                    int M, int N, int K) {
    __shared__ short A_s[128 * 56];
    __shared__ short B_s[128 * 56];
    const int t = threadIdx.x;
    const int bm = blockIdx.y * 128, bn = blockIdx.x * 128;
    const int lane = t & 63, w = t >> 6;
    const int wr = w >> 1, wc = w & 1;
    const int fm = lane & 15, fq = lane >> 4;
    const int sr = t >> 1;
    const int sh = (t & 1) << 4;

    f32x4 acc[4][4];
#pragma unroll
    for (int i = 0; i < 4; i++)
#pragma unroll
        for (int j = 0; j < 4; j++) acc[i][j] = (f32x4){0.f, 0.f, 0.f, 0.f};

    for (int kt = 0; kt < K; kt += 32) {
        __syncthreads();
        if constexpr (sizeof(TA) == 4) {
            const float* ga = (const float*)A + (size_t)(bm + sr) * K + kt + sh;
            float4 f0 = *(const float4*)(ga);
            float4 f1 = *(const float4*)(ga + 4);
            float4 f2 = *(const float4*)(ga + 8);
            float4 f3 = *(const float4*)(ga + 12);
            *(short8*)&A_s[sr * 56 + sh] = pack8(f0, f1);
            *(short8*)&A_s[sr * 56 + sh + 8] = pack8(f2, f3);
        } else {
            const unsigned short* ga = (const unsigned short*)A + (size_t)(bm + sr) * K + kt + sh;
            *(short8*)&A_s[sr * 56 + sh]     = *(const short8*)(ga);
            *(short8*)&A_s[sr * 56 + sh + 8] = *(const short8*)(ga + 8);
        }
        {
            const float* gb = W + (size_t)(bn + sr) * K + kt + sh;
            float4 f0 = *(const float4*)(gb);
            float4 f1 = *(const float4*)(gb + 4);
            float4 f2 = *(const float4*)(gb + 8);
            float4 f3 = *(const float4*)(gb + 12);
            *(short8*)&B_s[sr * 56 + sh] = pack8(f0, f1);
            *(short8*)&B_s[sr * 56 + sh + 8] = pack8(f2, f3);
        }
        __syncthreads();
        short8 av[4], bv[4];
#pragma unroll
        for (int mt = 0; mt < 4; mt++)
            av[mt] = *(const short8*)&A_s[(wr * 64 + mt * 16 + fm) * 56 + fq * 8];
#pragma unroll
        for (int nt = 0; nt < 4; nt++)
            bv[nt] = *(const short8*)&B_s[(wc * 64 + nt * 16 + fm) * 56 + fq * 8];
#pragma unroll
        for (int mt = 0; mt < 4; mt++)
#pragma unroll
            for (int nt = 0; nt < 4; nt++)
                acc[mt][nt] = __builtin_amdgcn_mfma_f32_16x16x32_bf16(
                    av[mt], bv[nt], acc[mt][nt], 0, 0, 0);
    }
#pragma unroll
    for (int mt = 0; mt < 4; mt++) {
        int row0 = bm + wr * 64 + mt * 16 + fq * 4;
#pragma unroll
        for (int nt = 0; nt < 4; nt++) {
            int col = bn + wc * 64 + nt * 16 + fm;
            float bsv = bias[col];
#pragma unroll
            for (int r = 0; r < 4; r++) {
                float val = acc[mt][nt][r] + bsv;
                if (RELU) val = fmaxf(val, 0.f);
                if constexpr (sizeof(TC) == 4)
                    ((float*)C)[(size_t)(row0 + r) * N + col] = val;
                else
                    ((unsigned short*)C)[(size_t)(row0 + r) * N + col] = f2bf(val);
            }
        }
    }
}

// ---------- flash-style attention with distance decay ----------
// Block = 64 Q-rows of one (b,h); 4 waves, wave w owns rows w*16..w*16+15.
// Pass 1: online (rowmax, unmasked-sum, masked-sum) over recomputable scores.
// Pass 2: recompute scores chunk-by-chunk, masked cumsum via width-16 scans +
// carry, decay rescale, online softmax#2 with PV accumulation (MFMA).
__global__ __launch_bounds__(256, 2) void attn_flash(
    const float* __restrict__ Q, const float* __restrict__ Kg,
    const float* __restrict__ Vg, const float* __restrict__ gammas,
    const int* __restrict__ maskp, float* __restrict__ out) {
    __shared__ short Qs[64 * 72];        //  9.2 KB  Q tile [i][d] bf16
    __shared__ short Ks[JC2 * 72];       // 18.4 KB  K chunk [j][d] bf16
    __shared__ short Vts[64 * 136];      // 17.4 KB  V chunk transposed [d][j]
    __shared__ short Ps[4 * 16 * 136];   // 17.4 KB  per-wave P tile [i][j]

    const int t = threadIdx.x;
    const int lane = t & 63, w = t >> 6;
    const int col = lane & 15;           // MFMA n-index / j-in-group / d-in-group
    const int quad = lane >> 4;

    const int bid = blockIdx.x;          // ((b*H)+h)*16 + it
    const int it = bid & 15;
    const int bh = bid >> 4;
    const int h = bh & (HH - 1);
    const int b = bh >> 4;
    const int i0 = it * 64;
    const int mask = *maskp;

    const float g0 = gammas[h];
    const float gamma = -((g0 > 20.f) ? g0 : log1pf(__expf(g0)));

    const size_t qbase = ((size_t)(b * SS + i0)) * DDIM + h * DKK;
    const size_t kvbase = ((size_t)b * SS) * DDIM + h * DKK;

    // ---- stage Q tile (once) ----
    {
        int r = t >> 2, d0 = (t & 3) << 4;
        const float* gq = Q + qbase + (size_t)r * DDIM + d0;
        float4 f0 = *(const float4*)(gq);
        float4 f1 = *(const float4*)(gq + 4);
        float4 f2 = *(const float4*)(gq + 8);
        float4 f3 = *(const float4*)(gq + 12);
        *(short8*)&Qs[r * 72 + d0] = pack8(f0, f1);
        *(short8*)&Qs[r * 72 + d0 + 8] = pack8(f2, f3);
    }
    __syncthreads();
    const short8 qa0 = *(const short8*)&Qs[(w * 16 + col) * 72 + quad * 8];
    const short8 qa1 = *(const short8*)&Qs[(w * 16 + col) * 72 + 32 + quad * 8];

    // per-reg row metadata (C-frag rows: quad*4 + r)
    float m1[4], su[4], smT[4], gi4[4];
    int lim4[4];
#pragma unroll
    for (int r = 0; r < 4; ++r) {
        m1[r] = -3.4e38f; su[r] = 0.f; smT[r] = 0.f;
        int gi = i0 + w * 16 + quad * 4 + r;
        gi4[r] = (float)gi;
        lim4[r] = gi + mask;
    }

    // ======== pass 1 ========
    for (int ck = 0; ck < SS / JC2; ++ck) {
        const int jc = ck * JC2;
        __syncthreads();
        {   // stage K chunk
            int j = t >> 1, d0 = (t & 1) << 5;
            const float* gk = Kg + kvbase + (size_t)(jc + j) * DDIM + d0;
            float4 f0 = *(const float4*)(gk);
            float4 f1 = *(const float4*)(gk + 4);
            float4 f2 = *(const float4*)(gk + 8);
            float4 f3 = *(const float4*)(gk + 12);
            float4 f4 = *(const float4*)(gk + 16);
            float4 f5 = *(const float4*)(gk + 20);
            float4 f6 = *(const float4*)(gk + 24);
            float4 f7 = *(const float4*)(gk + 28);
            *(short8*)&Ks[j * 72 + d0]      = pack8(f0, f1);
            *(short8*)&Ks[j * 72 + d0 + 8]  = pack8(f2, f3);
            *(short8*)&Ks[j * 72 + d0 + 16] = pack8(f4, f5);
            *(short8*)&Ks[j * 72 + d0 + 24] = pack8(f6, f7);
        }
        __syncthreads();
#pragma unroll
        for (int g = 0; g < 8; ++g) {
            short8 kb0 = *(const short8*)&Ks[(g * 16 + col) * 72 + quad * 8];
            short8 kb1 = *(const short8*)&Ks[(g * 16 + col) * 72 + 32 + quad * 8];
            f32x4 c = (f32x4){0.f, 0.f, 0.f, 0.f};
            c = __builtin_amdgcn_mfma_f32_16x16x32_bf16(qa0, kb0, c, 0, 0, 0);
            c = __builtin_amdgcn_mfma_f32_16x16x32_bf16(qa1, kb1, c, 0, 0, 0);
            int j = jc + g * 16 + col;
#pragma unroll
            for (int r = 0; r < 4; ++r) {
                float s = c[r] * 0.125f;
                float mn = fmaxf(m1[r], s);
                float esc = __expf(m1[r] - mn);
                float ev = __expf(s - mn);
                su[r] = su[r] * esc + ev;
                smT[r] = smT[r] * esc + ((j < lim4[r]) ? ev : 0.f);
                m1[r] = mn;
            }
        }
    }
    // merge across the 16 lanes of each quad (rows identical within quad)
#pragma unroll
    for (int off = 1; off < 16; off <<= 1) {
#pragma unroll
        for (int r = 0; r < 4; ++r) {
            float mo = __shfl_xor(m1[r], off, 16);
            float so = __shfl_xor(su[r], off, 16);
            float to = __shfl_xor(smT[r], off, 16);
            float M = fmaxf(m1[r], mo);
            float e1 = __expf(m1[r] - M), e2 = __expf(mo - M);
            su[r] = su[r] * e1 + so * e2;
            smT[r] = smT[r] * e1 + to * e2;
            m1[r] = M;
        }
    }
    float invu[4];
#pragma unroll
    for (int r = 0; r < 4; ++r) invu[r] = 1.f / su[r];

    // ======== pass 2 ========
    float m2[4], l2[4], carry[4];
    f32x4 o[4];
#pragma unroll
    for (int r = 0; r < 4; ++r) { m2[r] = -3.4e38f; l2[r] = 0.f; carry[r] = 0.f; }
#pragma unroll
    for (int dg = 0; dg < 4; ++dg) o[dg] = (f32x4){0.f, 0.f, 0.f, 0.f};

    short* Pw = &Ps[w * 16 * 136];

    for (int ck = 0; ck < SS / JC2; ++ck) {
        const int jc = ck * JC2;
        __syncthreads();
        {   // stage K chunk
            int j = t >> 1, d0 = (t & 1) << 5;
            const float* gk = Kg + kvbase + (size_t)(jc + j) * DDIM + d0;
            float4 f0 = *(const float4*)(gk);
            float4 f1 = *(const float4*)(gk + 4);
            float4 f2 = *(const float4*)(gk + 8);
            float4 f3 = *(const float4*)(gk + 12);
            float4 f4 = *(const float4*)(gk + 16);
            float4 f5 = *(const float4*)(gk + 20);
            float4 f6 = *(const float4*)(gk + 24);
            float4 f7 = *(const float4*)(gk + 28);
            *(short8*)&Ks[j * 72 + d0]      = pack8(f0, f1);
            *(short8*)&Ks[j * 72 + d0 + 8]  = pack8(f2, f3);
            *(short8*)&Ks[j * 72 + d0 + 16] = pack8(f4, f5);
            *(short8*)&Ks[j * 72 + d0 + 24] = pack8(f6, f7);
        }
        {   // stage V chunk transposed: Vts[d][j]
            int j = t >> 1, d0 = (t & 1) << 5;
            const float* gv = Vg + kvbase + (size_t)(jc + j) * DDIM + d0;
#pragma unroll
            for (int q8 = 0; q8 < 8; ++q8) {
                float4 f = *(const float4*)(gv + q8 * 4);
                Vts[(d0 + q8 * 4 + 0) * 136 + j] = (short)f2bf(f.x);
                Vts[(d0 + q8 * 4 + 1) * 136 + j] = (short)f2bf(f.y);
                Vts[(d0 + q8 * 4 + 2) * 136 + j] = (short)f2bf(f.z);
                Vts[(d0 + q8 * 4 + 3) * 136 + j] = (short)f2bf(f.w);
            }
        }
        __syncthreads();

        f32x4 sf[8];
        float cm[4] = {-3.4e38f, -3.4e38f, -3.4e38f, -3.4e38f};
#pragma unroll
        for (int g = 0; g < 8; ++g) {
            short8 kb0 = *(const short8*)&Ks[(g * 16 + col) * 72 + quad * 8];
            short8 kb1 = *(const short8*)&Ks[(g * 16 + col) * 72 + 32 + quad * 8];
            f32x4 c = (f32x4){0.f, 0.f, 0.f, 0.f};
            c = __builtin_amdgcn_mfma_f32_16x16x32_bf16(qa0, kb0, c, 0, 0, 0);
            c = __builtin_amdgcn_mfma_f32_16x16x32_bf16(qa1, kb1, c, 0, 0, 0);
            int j = jc + g * 16 + col;
            float sv[4], incl[4];
#pragma unroll
            for (int r = 0; r < 4; ++r) {
                sv[r] = c[r] * 0.125f;
                float p = __expf(sv[r] - m1[r]);
                incl[r] = (j < lim4[r]) ? p : 0.f;
            }
            // inclusive scan over the 16 lanes of this quad (j order)
#pragma unroll
            for (int dd = 1; dd < 16; dd <<= 1) {
#pragma unroll
                for (int r = 0; r < 4; ++r) {
                    float tv = __shfl_up(incl[r], dd, 16);
                    if (col >= dd) incl[r] += tv;
                }
            }
#pragma unroll
            for (int r = 0; r < 4; ++r) {
                float grptot = __shfl(incl[r], 15, 16);
                float C = carry[r] + incl[r];          // inclusive masked cumsum
                carry[r] += grptot;
                float pos = fabsf((float)j - gi4[r]);
                float d2 = fmaxf((smT[r] - C) * invu[r] * pos, 0.f);
                float eff = fminf(fmaxf(__expf(gamma * sqrtf(d2)), 1e-5f), 1e5f);
                float sp = (j < lim4[r]) ? sv[r] * eff : -1e20f;
                sf[g][r] = sp;
                cm[r] = fmaxf(cm[r], sp);
            }
        }
        // chunk row-max, online rescale
#pragma unroll
        for (int off = 1; off < 16; off <<= 1)
#pragma unroll
            for (int r = 0; r < 4; ++r)
                cm[r] = fmaxf(cm[r], __shfl_xor(cm[r], off, 16));
        float alpha[4], padd[4];
#pragma unroll
        for (int r = 0; r < 4; ++r) {
            float mn = fmaxf(m2[r], cm[r]);
            alpha[r] = __expf(m2[r] - mn);
            m2[r] = mn;
            l2[r] *= alpha[r];
            padd[r] = 0.f;
        }
#pragma unroll
        for (int dg = 0; dg < 4; ++dg)
#pragma unroll
            for (int r = 0; r < 4; ++r) o[dg][r] *= alpha[r];
        // p2 numerators -> LDS P tile (C-layout rows -> [i][j] row-major)
#pragma unroll
        for (int g = 0; g < 8; ++g)
#pragma unroll
            for (int r = 0; r < 4; ++r) {
                float p = __expf(sf[g][r] - m2[r]);
                padd[r] += p;
                Pw[(quad * 4 + r) * 136 + g * 16 + col] = (short)f2bf(p);
            }
#pragma unroll
        for (int off = 1; off < 16; off <<= 1)
#pragma unroll
            for (int r = 0; r < 4; ++r) padd[r] += __shfl_xor(padd[r], off, 16);
#pragma unroll
        for (int r = 0; r < 4; ++r) l2[r] += padd[r];
        __syncthreads();   // P writes visible (cross-lane A-frag reads)
        // PV: o[i][d] += P[i][j] * V[j][d]
#pragma unroll
        for (int kg = 0; kg < 4; ++kg) {
            short8 pa = *(const short8*)&Pw[col * 136 + kg * 32 + quad * 8];
#pragma unroll
            for (int dg = 0; dg < 4; ++dg) {
                short8 vb = *(const short8*)&Vts[(dg * 16 + col) * 136 + kg * 32 + quad * 8];
                o[dg] = __builtin_amdgcn_mfma_f32_16x16x32_bf16(pa, vb, o[dg], 0, 0, 0);
            }
        }
    }

    // ---- epilogue ----
#pragma unroll
    for (int r = 0; r < 4; ++r) {
        int irow = i0 + w * 16 + quad * 4 + r;
        float scl = 1.f / l2[r];
        if (mask == 0 && irow == 0) scl = 0.f;   // reference zero-pads row 0
        size_t base = ((size_t)(b * SS) + irow) * DDIM + h * DKK;
#pragma unroll
        for (int dg = 0; dg < 4; ++dg)
            out[base + dg * 16 + col] = o[dg][r] * scl;
    }
}

// ---------- fused residual-add + LayerNorm (+ optional bf16 copy) ----------
template <bool WB>
__global__ __launch_bounds__(256) void add_ln(const float* __restrict__ R,
                                              const float* __restrict__ Y,
                                              const float* __restrict__ w,
                                              const float* __restrict__ bb,
                                              float* __restrict__ out,
                                              unsigned short* __restrict__ obf) {
    const int row = blockIdx.x;
    const int tid = threadIdx.x;
    __shared__ float red[4];
    __shared__ float xs[DDIM];
    const size_t base = (size_t)row * DDIM;
    float s = 0.f, s2 = 0.f;
#pragma unroll
    for (int l = 0; l < 4; l++) {
        int idx = tid + l * 256;
        float x = R[base + idx] + Y[base + idx];
        xs[idx] = x;
        s += x;
        s2 += x * x;
    }
    s = block_reduce_sum(s, red, tid);
    s2 = block_reduce_sum(s2, red, tid);
    const float mu = s * (1.f / DDIM);
    const float var = s2 * (1.f / DDIM) - mu * mu;
    const float rstd = rsqrtf(var + 1e-5f);
#pragma unroll
    for (int l = 0; l < 4; l++) {
        int idx = tid + l * 256;
        float v = (xs[idx] - mu) * rstd * w[idx] + bb[idx];
        out[base + idx] = v;
        if (WB) obf[base + idx] = f2bf(v);
    }
}

extern "C" void kernel_launch(void* const* d_in, const int* in_sizes, int n_in,
                              void* d_out, int out_size, void* d_ws, size_t ws_size,
                              hipStream_t stream) {
    const int*   maskp  = (const int*)d_in[0];
    const float* query  = (const float*)d_in[1];
    const float* key    = (const float*)d_in[2];
    const float* values = (const float*)d_in[3];
    const float* Wq = (const float*)d_in[4];
    const float* bq = (const float*)d_in[5];
    const float* Wk = (const float*)d_in[6];
    const float* bk = (const float*)d_in[7];
    const float* Wv = (const float*)d_in[8];
    const float* bv = (const float*)d_in[9];
    const float* Wo = (const float*)d_in[10];
    const float* bo = (const float*)d_in[11];
    const float* gammas = (const float*)d_in[12];
    const float* ln1w = (const float*)d_in[13];
    const float* ln1b = (const float*)d_in[14];
    const float* W1 = (const float*)d_in[15];
    const float* b1 = (const float*)d_in[16];
    const float* W2 = (const float*)d_in[17];
    const float* b2 = (const float*)d_in[18];
    const float* ln2w = (const float*)d_in[19];
    const float* ln2b = (const float*)d_in[20];

    const int M = BB * SS;                 // 4096 rows
    float* ws = (float*)d_ws;
    float* bQ   = ws;                               // 16 MB fp32
    float* bK   = ws + (size_t)4194304;             // 16 MB
    float* bV   = ws + (size_t)8388608;             // 16 MB
    float* bATT = ws + (size_t)12582912;            // 16 MB
    unsigned short* hidden = (unsigned short*)(ws + (size_t)16777216);            // 32 MB bf16
    unsigned short* x_bf   = (unsigned short*)(ws + (size_t)16777216 + 8388608);  // 8 MB bf16

    dim3 blk(256);

    // QKV projections (bf16 MFMA)
    gemm_mfma<float, float, false><<<dim3(8, 32), blk, 0, stream>>>(query,  Wq, bq, bQ, M, DDIM, DDIM);
    gemm_mfma<float, float, false><<<dim3(8, 32), blk, 0, stream>>>(key,    Wk, bk, bK, M, DDIM, DDIM);
    gemm_mfma<float, float, false><<<dim3(8, 32), blk, 0, stream>>>(values, Wv, bv, bV, M, DDIM, DDIM);

    // attention (flash-style, no score scratch)
    attn_flash<<<dim3(BB * HH * 16), blk, 0, stream>>>(bQ, bK, bV, gammas, maskp, bATT);

    // output projection -> bQ (Q dead)
    gemm_mfma<float, float, false><<<dim3(8, 32), blk, 0, stream>>>(bATT, Wo, bo, bQ, M, DDIM, DDIM);

    // x = LN(query + attn_out) -> bK fp32 + x_bf bf16
    add_ln<true><<<dim3(M), blk, 0, stream>>>(query, bQ, ln1w, ln1b, bK, x_bf);

    // hidden = relu(x @ W1^T + b1) -> bf16
    gemm_mfma<unsigned short, unsigned short, true><<<dim3(32, 32), blk, 0, stream>>>(x_bf, W1, b1, hidden, M, DFFF, DDIM);

    // y = hidden @ W2^T + b2 -> bQ fp32
    gemm_mfma<unsigned short, float, false><<<dim3(8, 32), blk, 0, stream>>>(hidden, W2, b2, bQ, M, DDIM, DFFF);

    // out = LN(x + y) -> d_out (fp32)
    add_ln<false><<<dim3(M), blk, 0, stream>>>(bK, bQ, ln2w, ln2b, (float*)d_out, nullptr);
}

// Round 7
// 547.378 us; speedup vs baseline: 13.4530x; 1.6262x over previous
//
#include <hip/hip_runtime.h>
#include <hip/hip_bf16.h>
#include <math.h>

#define BB   4
#define SS   1024
#define DDIM 1024
#define HH   16
#define DKK  64
#define DFFF 4096
#define JC2  128     // K/V j-chunk per LDS stage (attention)

typedef __attribute__((ext_vector_type(8))) short short8;
typedef __attribute__((ext_vector_type(4))) float f32x4;
typedef unsigned short ushort;

__device__ __forceinline__ ushort f2bf(float f) {   // RNE fp32->bf16
    unsigned int u = __float_as_uint(f);
    unsigned int r = (u + 0x7FFFu + ((u >> 16) & 1u)) >> 16;
    return (ushort)r;
}
__device__ __forceinline__ short8 pack8(float4 f0, float4 f1) {
    short8 s;
    s[0] = (short)f2bf(f0.x); s[1] = (short)f2bf(f0.y);
    s[2] = (short)f2bf(f0.z); s[3] = (short)f2bf(f0.w);
    s[4] = (short)f2bf(f1.x); s[5] = (short)f2bf(f1.y);
    s[6] = (short)f2bf(f1.z); s[7] = (short)f2bf(f1.w);
    return s;
}

// async global->LDS, 16B per lane; LDS dest = wave-uniform base + lane*16
#define GLD16(g, l) __builtin_amdgcn_global_load_lds( \
    (const __attribute__((address_space(1))) unsigned int*)(g), \
    (__attribute__((address_space(3))) unsigned int*)(l), 16, 0, 0)

// ---------- block reductions (256 threads = 4 waves of 64) ----------
__device__ __forceinline__ float block_reduce_sum(float v, float* red, int tid) {
#pragma unroll
    for (int off = 32; off; off >>= 1) v += __shfl_xor(v, off);
    __syncthreads();
    if ((tid & 63) == 0) red[tid >> 6] = v;
    __syncthreads();
    return red[0] + red[1] + red[2] + red[3];
}

// ---------- fp32 -> bf16 batch convert, per-segment sizes ----------
// seg elems: q/k/v = 4M; Wq/Wk/Wv/Wo = 1M (D*D); W1/W2 = 4M.  (r6 bug: OOB)
struct CvtArgs { const float* s[9]; ushort* d[9]; unsigned int n[9]; };
__global__ __launch_bounds__(256) void convert_bf(CvtArgs a) {
    const int seg = blockIdx.y;
    size_t idx = ((size_t)blockIdx.x * 256 + threadIdx.x) * 8;
    if (idx >= a.n[seg]) return;
    const float* s = a.s[seg];
    float4 f0 = *(const float4*)(s + idx);
    float4 f1 = *(const float4*)(s + idx + 4);
    *(short8*)(a.d[seg] + idx) = pack8(f0, f1);
}

// ---------- bf16 MFMA GEMM (m97-style): C = act(A[M,K] @ W[N,K]^T + bias) ----
// BM x 128 tile, BK=64, 256 thr / 4 waves; wave = (BM/2) x 64 via 16x16x32 MFMA.
// global_load_lds 16B staging; XOR-swizzled LDS (chunk = g ^ (row&7)) since the
// wave-uniform dest forbids padding; frag reads then spread over all 32 banks.
template <int BM, typename TC, bool RELU>
__global__ __launch_bounds__(256, 2) void gemm_bf(const ushort* __restrict__ A,
                                                  const ushort* __restrict__ Bm,
                                                  const float* __restrict__ bias,
                                                  TC* __restrict__ C,
                                                  int M, int N, int K) {
    constexpr int MT = BM / 32;           // m-frags per wave
    constexpr int PA = BM / 32;           // A staging iters per wave
    __shared__ ushort A_s[BM * 64];
    __shared__ ushort B_s[128 * 64];
    const int t = threadIdx.x;
    const int bm = blockIdx.y * BM, bn = blockIdx.x * 128;
    const int lane = t & 63, w = t >> 6;
    const int wr = w >> 1, wc = w & 1;
    const int fm = lane & 15, fq = lane >> 4;
    const int srl = lane >> 3;            // staging row-in-group
    const int sg8 = ((lane & 7) ^ srl) << 3;   // swizzled global k offset

    f32x4 acc[MT][4];
#pragma unroll
    for (int mt = 0; mt < MT; mt++)
#pragma unroll
        for (int nt = 0; nt < 4; nt++) acc[mt][nt] = (f32x4){0.f, 0.f, 0.f, 0.f};

    for (int kt = 0; kt < K; kt += 64) {
        __syncthreads();
#pragma unroll
        for (int p = 0; p < PA; ++p) {
            int rowg = (w * PA + p) * 8;
            GLD16(A + (size_t)(bm + rowg + srl) * K + kt + sg8, &A_s[rowg * 64]);
        }
#pragma unroll
        for (int p = 0; p < 4; ++p) {
            int rowg = (w * 4 + p) * 8;
            GLD16(Bm + (size_t)(bn + rowg + srl) * K + kt + sg8, &B_s[rowg * 64]);
        }
        __syncthreads();                  // drains vmcnt (incl. lds-DMA)

        short8 av[2][MT], bv[2][4];
        const int sw = fm & 7;
#pragma unroll
        for (int mt = 0; mt < MT; ++mt) {
            int row = wr * (BM / 2) + mt * 16 + fm;
#pragma unroll
            for (int ks = 0; ks < 2; ++ks)
                av[ks][mt] = *(const short8*)&A_s[row * 64 + (((ks * 4 + fq) ^ sw) << 3)];
        }
#pragma unroll
        for (int nt = 0; nt < 4; ++nt) {
            int row = wc * 64 + nt * 16 + fm;
#pragma unroll
            for (int ks = 0; ks < 2; ++ks)
                bv[ks][nt] = *(const short8*)&B_s[row * 64 + (((ks * 4 + fq) ^ sw) << 3)];
        }
#pragma unroll
        for (int ks = 0; ks < 2; ++ks)
#pragma unroll
            for (int mt = 0; mt < MT; ++mt)
#pragma unroll
                for (int nt = 0; nt < 4; ++nt)
                    acc[mt][nt] = __builtin_amdgcn_mfma_f32_16x16x32_bf16(
                        av[ks][mt], bv[ks][nt], acc[mt][nt], 0, 0, 0);
    }

    // epilogue: D row = fq*4+reg, col = fm (verified r4/r5)
#pragma unroll
    for (int mt = 0; mt < MT; mt++) {
        int row0 = bm + wr * (BM / 2) + mt * 16 + fq * 4;
#pragma unroll
        for (int nt = 0; nt < 4; nt++) {
            int col = bn + wc * 64 + nt * 16 + fm;
            float bsv = bias[col];
#pragma unroll
            for (int r = 0; r < 4; r++) {
                float val = acc[mt][nt][r] + bsv;
                if (RELU) val = fmaxf(val, 0.f);
                if constexpr (sizeof(TC) == 4)
                    ((float*)C)[(size_t)(row0 + r) * N + col] = val;
                else
                    ((ushort*)C)[(size_t)(row0 + r) * N + col] = f2bf(val);
            }
        }
    }
}

// ---------- flash-style attention with distance decay (bf16 in/out) ----------
__global__ __launch_bounds__(256, 2) void attn_flash(
    const ushort* __restrict__ Q, const ushort* __restrict__ Kg,
    const ushort* __restrict__ Vg, const float* __restrict__ gammas,
    const int* __restrict__ maskp, ushort* __restrict__ out) {
    __shared__ short Qs[64 * 72];        // Q tile [i][d]
    __shared__ short Ks[JC2 * 72];       // K chunk [j][d]
    __shared__ short Vts[64 * 136];      // V chunk transposed [d][j]
    __shared__ short Ps[4 * 16 * 136];   // per-wave P tile [i][j]

    const int t = threadIdx.x;
    const int lane = t & 63, w = t >> 6;
    const int col = lane & 15;
    const int quad = lane >> 4;

    const int bid = blockIdx.x;          // ((b*H)+h)*16 + it
    const int it = bid & 15;
    const int bh = bid >> 4;
    const int h = bh & (HH - 1);
    const int b = bh >> 4;
    const int i0 = it * 64;
    const int mask = *maskp;

    const float g0 = gammas[h];
    const float gamma = -((g0 > 20.f) ? g0 : log1pf(__expf(g0)));

    const size_t qbase = ((size_t)(b * SS + i0)) * DDIM + h * DKK;
    const size_t kvbase = ((size_t)b * SS) * DDIM + h * DKK;

    {   // stage Q tile
        int r = t >> 2, d0 = (t & 3) << 4;
        const ushort* gq = Q + qbase + (size_t)r * DDIM + d0;
        *(short8*)&Qs[r * 72 + d0]     = *(const short8*)(gq);
        *(short8*)&Qs[r * 72 + d0 + 8] = *(const short8*)(gq + 8);
    }
    __syncthreads();
    const short8 qa0 = *(const short8*)&Qs[(w * 16 + col) * 72 + quad * 8];
    const short8 qa1 = *(const short8*)&Qs[(w * 16 + col) * 72 + 32 + quad * 8];

    float m1[4], su[4], smT[4], gi4[4];
    int lim4[4];
#pragma unroll
    for (int r = 0; r < 4; ++r) {
        m1[r] = -3.4e38f; su[r] = 0.f; smT[r] = 0.f;
        int gi = i0 + w * 16 + quad * 4 + r;
        gi4[r] = (float)gi;
        lim4[r] = gi + mask;
    }

    // ======== pass 1 ========
    for (int ck = 0; ck < SS / JC2; ++ck) {
        const int jc = ck * JC2;
        __syncthreads();
        {   int j = t >> 1, d0 = (t & 1) << 5;
            const ushort* gk = Kg + kvbase + (size_t)(jc + j) * DDIM + d0;
            *(short8*)&Ks[j * 72 + d0]      = *(const short8*)(gk);
            *(short8*)&Ks[j * 72 + d0 + 8]  = *(const short8*)(gk + 8);
            *(short8*)&Ks[j * 72 + d0 + 16] = *(const short8*)(gk + 16);
            *(short8*)&Ks[j * 72 + d0 + 24] = *(const short8*)(gk + 24);
        }
        __syncthreads();
#pragma unroll
        for (int g = 0; g < 8; ++g) {
            short8 kb0 = *(const short8*)&Ks[(g * 16 + col) * 72 + quad * 8];
            short8 kb1 = *(const short8*)&Ks[(g * 16 + col) * 72 + 32 + quad * 8];
            f32x4 c = (f32x4){0.f, 0.f, 0.f, 0.f};
            c = __builtin_amdgcn_mfma_f32_16x16x32_bf16(qa0, kb0, c, 0, 0, 0);
            c = __builtin_amdgcn_mfma_f32_16x16x32_bf16(qa1, kb1, c, 0, 0, 0);
            int j = jc + g * 16 + col;
#pragma unroll
            for (int r = 0; r < 4; ++r) {
                float s = c[r] * 0.125f;
                float mn = fmaxf(m1[r], s);
                float esc = __expf(m1[r] - mn);
                float ev = __expf(s - mn);
                su[r] = su[r] * esc + ev;
                smT[r] = smT[r] * esc + ((j < lim4[r]) ? ev : 0.f);
                m1[r] = mn;
            }
        }
    }
#pragma unroll
    for (int off = 1; off < 16; off <<= 1) {
#pragma unroll
        for (int r = 0; r < 4; ++r) {
            float mo = __shfl_xor(m1[r], off, 16);
            float so = __shfl_xor(su[r], off, 16);
            float to = __shfl_xor(smT[r], off, 16);
            float M = fmaxf(m1[r], mo);
            float e1 = __expf(m1[r] - M), e2 = __expf(mo - M);
            su[r] = su[r] * e1 + so * e2;
            smT[r] = smT[r] * e1 + to * e2;
            m1[r] = M;
        }
    }
    float invu[4];
#pragma unroll
    for (int r = 0; r < 4; ++r) invu[r] = 1.f / su[r];

    // ======== pass 2 ========
    float m2[4], l2[4], carry[4];
    f32x4 o[4];
#pragma unroll
    for (int r = 0; r < 4; ++r) { m2[r] = -3.4e38f; l2[r] = 0.f; carry[r] = 0.f; }
#pragma unroll
    for (int dg = 0; dg < 4; ++dg) o[dg] = (f32x4){0.f, 0.f, 0.f, 0.f};

    short* Pw = &Ps[w * 16 * 136];

    for (int ck = 0; ck < SS / JC2; ++ck) {
        const int jc = ck * JC2;
        __syncthreads();
        {   int j = t >> 1, d0 = (t & 1) << 5;
            const ushort* gk = Kg + kvbase + (size_t)(jc + j) * DDIM + d0;
            *(short8*)&Ks[j * 72 + d0]      = *(const short8*)(gk);
            *(short8*)&Ks[j * 72 + d0 + 8]  = *(const short8*)(gk + 8);
            *(short8*)&Ks[j * 72 + d0 + 16] = *(const short8*)(gk + 16);
            *(short8*)&Ks[j * 72 + d0 + 24] = *(const short8*)(gk + 24);
        }
        {   int j = t >> 1, d0 = (t & 1) << 5;
            const ushort* gv = Vg + kvbase + (size_t)(jc + j) * DDIM + d0;
            short8 v0 = *(const short8*)(gv);
            short8 v1 = *(const short8*)(gv + 8);
            short8 v2 = *(const short8*)(gv + 16);
            short8 v3 = *(const short8*)(gv + 24);
#pragma unroll
            for (int k = 0; k < 8; ++k) {
                Vts[(d0 + k) * 136 + j]      = v0[k];
                Vts[(d0 + 8 + k) * 136 + j]  = v1[k];
                Vts[(d0 + 16 + k) * 136 + j] = v2[k];
                Vts[(d0 + 24 + k) * 136 + j] = v3[k];
            }
        }
        __syncthreads();

        f32x4 sf[8];
        float cm[4] = {-3.4e38f, -3.4e38f, -3.4e38f, -3.4e38f};
#pragma unroll
        for (int g = 0; g < 8; ++g) {
            short8 kb0 = *(const short8*)&Ks[(g * 16 + col) * 72 + quad * 8];
            short8 kb1 = *(const short8*)&Ks[(g * 16 + col) * 72 + 32 + quad * 8];
            f32x4 c = (f32x4){0.f, 0.f, 0.f, 0.f};
            c = __builtin_amdgcn_mfma_f32_16x16x32_bf16(qa0, kb0, c, 0, 0, 0);
            c = __builtin_amdgcn_mfma_f32_16x16x32_bf16(qa1, kb1, c, 0, 0, 0);
            int j = jc + g * 16 + col;
            float sv[4], incl[4];
#pragma unroll
            for (int r = 0; r < 4; ++r) {
                sv[r] = c[r] * 0.125f;
                float p = __expf(sv[r] - m1[r]);
                incl[r] = (j < lim4[r]) ? p : 0.f;
            }
#pragma unroll
            for (int dd = 1; dd < 16; dd <<= 1) {
#pragma unroll
                for (int r = 0; r < 4; ++r) {
                    float tv = __shfl_up(incl[r], dd, 16);
                    if (col >= dd) incl[r] += tv;
                }
            }
#pragma unroll
            for (int r = 0; r < 4; ++r) {
                float grptot = __shfl(incl[r], 15, 16);
                float Cc = carry[r] + incl[r];
                carry[r] += grptot;
                float pos = fabsf((float)j - gi4[r]);
                float d2 = fmaxf((smT[r] - Cc) * invu[r] * pos, 0.f);
                float eff = fminf(fmaxf(__expf(gamma * sqrtf(d2)), 1e-5f), 1e5f);
                float sp = (j < lim4[r]) ? sv[r] * eff : -1e20f;
                sf[g][r] = sp;
                cm[r] = fmaxf(cm[r], sp);
            }
        }
#pragma unroll
        for (int off = 1; off < 16; off <<= 1)
#pragma unroll
            for (int r = 0; r < 4; ++r)
                cm[r] = fmaxf(cm[r], __shfl_xor(cm[r], off, 16));
        float alpha[4], padd[4];
#pragma unroll
        for (int r = 0; r < 4; ++r) {
            float mn = fmaxf(m2[r], cm[r]);
            alpha[r] = __expf(m2[r] - mn);
            m2[r] = mn;
            l2[r] *= alpha[r];
            padd[r] = 0.f;
        }
#pragma unroll
        for (int dg = 0; dg < 4; ++dg)
#pragma unroll
            for (int r = 0; r < 4; ++r) o[dg][r] *= alpha[r];
#pragma unroll
        for (int g = 0; g < 8; ++g)
#pragma unroll
            for (int r = 0; r < 4; ++r) {
                float p = __expf(sf[g][r] - m2[r]);
                padd[r] += p;
                Pw[(quad * 4 + r) * 136 + g * 16 + col] = (short)f2bf(p);
            }
#pragma unroll
        for (int off = 1; off < 16; off <<= 1)
#pragma unroll
            for (int r = 0; r < 4; ++r) padd[r] += __shfl_xor(padd[r], off, 16);
#pragma unroll
        for (int r = 0; r < 4; ++r) l2[r] += padd[r];
        __syncthreads();
#pragma unroll
        for (int kg = 0; kg < 4; ++kg) {
            short8 pa = *(const short8*)&Pw[col * 136 + kg * 32 + quad * 8];
#pragma unroll
            for (int dg = 0; dg < 4; ++dg) {
                short8 vb = *(const short8*)&Vts[(dg * 16 + col) * 136 + kg * 32 + quad * 8];
                o[dg] = __builtin_amdgcn_mfma_f32_16x16x32_bf16(pa, vb, o[dg], 0, 0, 0);
            }
        }
    }

#pragma unroll
    for (int r = 0; r < 4; ++r) {
        int irow = i0 + w * 16 + quad * 4 + r;
        float scl = 1.f / l2[r];
        if (mask == 0 && irow == 0) scl = 0.f;
        size_t base = ((size_t)(b * SS) + irow) * DDIM + h * DKK;
#pragma unroll
        for (int dg = 0; dg < 4; ++dg)
            out[base + dg * 16 + col] = f2bf(o[dg][r] * scl);
    }
}

// ---------- fused residual-add + LayerNorm (+ optional bf16 copy) ----------
template <bool WB>
__global__ __launch_bounds__(256) void add_ln(const float* __restrict__ R,
                                              const float* __restrict__ Y,
                                              const float* __restrict__ w,
                                              const float* __restrict__ bb,
                                              float* __restrict__ out,
                                              ushort* __restrict__ obf) {
    const int row = blockIdx.x;
    const int tid = threadIdx.x;
    __shared__ float red[4];
    __shared__ float xs[DDIM];
    const size_t base = (size_t)row * DDIM;
    float s = 0.f, s2 = 0.f;
#pragma unroll
    for (int l = 0; l < 4; l++) {
        int idx = tid + l * 256;
        float x = R[base + idx] + Y[base + idx];
        xs[idx] = x;
        s += x;
        s2 += x * x;
    }
    s = block_reduce_sum(s, red, tid);
    s2 = block_reduce_sum(s2, red, tid);
    const float mu = s * (1.f / DDIM);
    const float var = s2 * (1.f / DDIM) - mu * mu;
    const float rstd = rsqrtf(var + 1e-5f);
#pragma unroll
    for (int l = 0; l < 4; l++) {
        int idx = tid + l * 256;
        float v = (xs[idx] - mu) * rstd * w[idx] + bb[idx];
        out[base + idx] = v;
        if (WB) obf[base + idx] = f2bf(v);
    }
}

extern "C" void kernel_launch(void* const* d_in, const int* in_sizes, int n_in,
                              void* d_out, int out_size, void* d_ws, size_t ws_size,
                              hipStream_t stream) {
    const int*   maskp  = (const int*)d_in[0];
    const float* query  = (const float*)d_in[1];
    const float* key    = (const float*)d_in[2];
    const float* values = (const float*)d_in[3];
    const float* Wq = (const float*)d_in[4];
    const float* bq = (const float*)d_in[5];
    const float* Wk = (const float*)d_in[6];
    const float* bk = (const float*)d_in[7];
    const float* Wv = (const float*)d_in[8];
    const float* bv = (const float*)d_in[9];
    const float* Wo = (const float*)d_in[10];
    const float* bo = (const float*)d_in[11];
    const float* gammas = (const float*)d_in[12];
    const float* ln1w = (const float*)d_in[13];
    const float* ln1b = (const float*)d_in[14];
    const float* W1 = (const float*)d_in[15];
    const float* b1 = (const float*)d_in[16];
    const float* W2 = (const float*)d_in[17];
    const float* b2 = (const float*)d_in[18];
    const float* ln2w = (const float*)d_in[19];
    const float* ln2b = (const float*)d_in[20];

    const int M = BB * SS;                 // 4096 rows
    const size_t MB = 1048576;
    char* wsb = (char*)d_ws;
    // 0..48MB: bf16 weights; 48..72: bf16 inputs (later x/x_bf); 72..96: Q/K/V
    // bf16 (later hidden); 96..104: ATT bf16 (later hidden tail); 104..120: Y
    ushort* Wq_bf = (ushort*)(wsb + 0 * MB);
    ushort* Wk_bf = (ushort*)(wsb + 8 * MB);
    ushort* Wv_bf = (ushort*)(wsb + 16 * MB);
    ushort* Wo_bf = (ushort*)(wsb + 24 * MB);
    ushort* W1_bf = (ushort*)(wsb + 32 * MB);
    ushort* W2_bf = (ushort*)(wsb + 40 * MB);
    ushort* qi_bf = (ushort*)(wsb + 48 * MB);
    ushort* ki_bf = (ushort*)(wsb + 56 * MB);
    ushort* vi_bf = (ushort*)(wsb + 64 * MB);
    ushort* Qb    = (ushort*)(wsb + 72 * MB);
    ushort* Kb    = (ushort*)(wsb + 80 * MB);
    ushort* Vb    = (ushort*)(wsb + 88 * MB);
    ushort* ATTb  = (ushort*)(wsb + 96 * MB);
    float*  Yf    = (float*)(wsb + 104 * MB);
    float*  xf    = (float*)(wsb + 48 * MB);    // alias qi/ki (dead after QKV)
    ushort* x_bf  = (ushort*)(wsb + 64 * MB);   // alias vi
    ushort* hidden= (ushort*)(wsb + 72 * MB);   // alias Q/K/V/ATT (dead)

    dim3 blk(256);

    // batch convert fp32 -> bf16 with correct per-segment sizes
    const unsigned int N4M = 4u * 1024 * 1024, N1M = 1024 * 1024;
    CvtArgs ca;
    ca.s[0] = query; ca.s[1] = key; ca.s[2] = values;
    ca.s[3] = Wq; ca.s[4] = Wk; ca.s[5] = Wv; ca.s[6] = Wo;
    ca.s[7] = W1; ca.s[8] = W2;
    ca.d[0] = qi_bf; ca.d[1] = ki_bf; ca.d[2] = vi_bf;
    ca.d[3] = Wq_bf; ca.d[4] = Wk_bf; ca.d[5] = Wv_bf; ca.d[6] = Wo_bf;
    ca.d[7] = W1_bf; ca.d[8] = W2_bf;
    ca.n[0] = N4M; ca.n[1] = N4M; ca.n[2] = N4M;
    ca.n[3] = N1M; ca.n[4] = N1M; ca.n[5] = N1M; ca.n[6] = N1M;
    ca.n[7] = N4M; ca.n[8] = N4M;
    convert_bf<<<dim3(2048, 9), blk, 0, stream>>>(ca);

    // QKV projections -> bf16
    gemm_bf<64, ushort, false><<<dim3(8, 64), blk, 0, stream>>>(qi_bf, Wq_bf, bq, Qb, M, DDIM, DDIM);
    gemm_bf<64, ushort, false><<<dim3(8, 64), blk, 0, stream>>>(ki_bf, Wk_bf, bk, Kb, M, DDIM, DDIM);
    gemm_bf<64, ushort, false><<<dim3(8, 64), blk, 0, stream>>>(vi_bf, Wv_bf, bv, Vb, M, DDIM, DDIM);

    // attention (flash-style, bf16 in/out)
    attn_flash<<<dim3(BB * HH * 16), blk, 0, stream>>>(Qb, Kb, Vb, gammas, maskp, ATTb);

    // output projection -> fp32 Y
    gemm_bf<64, float, false><<<dim3(8, 64), blk, 0, stream>>>(ATTb, Wo_bf, bo, Yf, M, DDIM, DDIM);

    // x = LN(query + Y) -> xf fp32 + x_bf
    add_ln<true><<<dim3(M), blk, 0, stream>>>(query, Yf, ln1w, ln1b, xf, x_bf);

    // hidden = relu(x @ W1^T + b1) -> bf16
    gemm_bf<128, ushort, true><<<dim3(32, 32), blk, 0, stream>>>(x_bf, W1_bf, b1, hidden, M, DFFF, DDIM);

    // y = hidden @ W2^T + b2 -> fp32 Y
    gemm_bf<64, float, false><<<dim3(8, 64), blk, 0, stream>>>(hidden, W2_bf, b2, Yf, M, DDIM, DFFF);

    // out = LN(x + y) -> d_out (fp32)
    add_ln<false><<<dim3(M), blk, 0, stream>>>(xf, Yf, ln2w, ln2b, (float*)d_out, nullptr);
}

// Round 8
// 523.446 us; speedup vs baseline: 14.0681x; 1.0457x over previous
//
#include <hip/hip_runtime.h>
#include <hip/hip_bf16.h>
#include <math.h>

#define BB   4
#define SS   1024
#define DDIM 1024
#define HH   16
#define DKK  64
#define DFFF 4096
#define JC2  64      // K/V j-chunk per LDS stage (attention); 64 -> 27.6 KB LDS

typedef __attribute__((ext_vector_type(8))) short short8;
typedef __attribute__((ext_vector_type(4))) float f32x4;
typedef unsigned short ushort;

__device__ __forceinline__ ushort f2bf(float f) {   // RNE fp32->bf16
    unsigned int u = __float_as_uint(f);
    unsigned int r = (u + 0x7FFFu + ((u >> 16) & 1u)) >> 16;
    return (ushort)r;
}
__device__ __forceinline__ short8 pack8(float4 f0, float4 f1) {
    short8 s;
    s[0] = (short)f2bf(f0.x); s[1] = (short)f2bf(f0.y);
    s[2] = (short)f2bf(f0.z); s[3] = (short)f2bf(f0.w);
    s[4] = (short)f2bf(f1.x); s[5] = (short)f2bf(f1.y);
    s[6] = (short)f2bf(f1.z); s[7] = (short)f2bf(f1.w);
    return s;
}

// async global->LDS, 16B per lane; LDS dest = wave-uniform base + lane*16
#define GLD16(g, l) __builtin_amdgcn_global_load_lds( \
    (const __attribute__((address_space(1))) unsigned int*)(g), \
    (__attribute__((address_space(3))) unsigned int*)(l), 16, 0, 0)

// ---------- block reductions (256 threads = 4 waves of 64) ----------
__device__ __forceinline__ float block_reduce_sum(float v, float* red, int tid) {
#pragma unroll
    for (int off = 32; off; off >>= 1) v += __shfl_xor(v, off);
    __syncthreads();
    if ((tid & 63) == 0) red[tid >> 6] = v;
    __syncthreads();
    return red[0] + red[1] + red[2] + red[3];
}

// ---------- fp32 -> bf16 batch convert, per-segment sizes ----------
struct CvtArgs { const float* s[9]; ushort* d[9]; unsigned int n[9]; };
__global__ __launch_bounds__(256) void convert_bf(CvtArgs a) {
    const int seg = blockIdx.y;
    size_t idx = ((size_t)blockIdx.x * 256 + threadIdx.x) * 8;
    if (idx >= a.n[seg]) return;
    const float* s = a.s[seg];
    float4 f0 = *(const float4*)(s + idx);
    float4 f1 = *(const float4*)(s + idx + 4);
    *(short8*)(a.d[seg] + idx) = pack8(f0, f1);
}

// ---------- bf16 MFMA GEMM (m97-style): C = act(A[M,K] @ W[N,K]^T + bias) ----
// (unchanged from round 7 — verified)
template <int BM, typename TC, bool RELU>
__global__ __launch_bounds__(256, 2) void gemm_bf(const ushort* __restrict__ A,
                                                  const ushort* __restrict__ Bm,
                                                  const float* __restrict__ bias,
                                                  TC* __restrict__ C,
                                                  int M, int N, int K) {
    constexpr int MT = BM / 32;           // m-frags per wave
    constexpr int PA = BM / 32;           // A staging iters per wave
    __shared__ ushort A_s[BM * 64];
    __shared__ ushort B_s[128 * 64];
    const int t = threadIdx.x;
    const int bm = blockIdx.y * BM, bn = blockIdx.x * 128;
    const int lane = t & 63, w = t >> 6;
    const int wr = w >> 1, wc = w & 1;
    const int fm = lane & 15, fq = lane >> 4;
    const int srl = lane >> 3;            // staging row-in-group
    const int sg8 = ((lane & 7) ^ srl) << 3;   // swizzled global k offset

    f32x4 acc[MT][4];
#pragma unroll
    for (int mt = 0; mt < MT; mt++)
#pragma unroll
        for (int nt = 0; nt < 4; nt++) acc[mt][nt] = (f32x4){0.f, 0.f, 0.f, 0.f};

    for (int kt = 0; kt < K; kt += 64) {
        __syncthreads();
#pragma unroll
        for (int p = 0; p < PA; ++p) {
            int rowg = (w * PA + p) * 8;
            GLD16(A + (size_t)(bm + rowg + srl) * K + kt + sg8, &A_s[rowg * 64]);
        }
#pragma unroll
        for (int p = 0; p < 4; ++p) {
            int rowg = (w * 4 + p) * 8;
            GLD16(Bm + (size_t)(bn + rowg + srl) * K + kt + sg8, &B_s[rowg * 64]);
        }
        __syncthreads();                  // drains vmcnt (incl. lds-DMA)

        short8 av[2][MT], bv[2][4];
        const int sw = fm & 7;
#pragma unroll
        for (int mt = 0; mt < MT; ++mt) {
            int row = wr * (BM / 2) + mt * 16 + fm;
#pragma unroll
            for (int ks = 0; ks < 2; ++ks)
                av[ks][mt] = *(const short8*)&A_s[row * 64 + (((ks * 4 + fq) ^ sw) << 3)];
        }
#pragma unroll
        for (int nt = 0; nt < 4; ++nt) {
            int row = wc * 64 + nt * 16 + fm;
#pragma unroll
            for (int ks = 0; ks < 2; ++ks)
                bv[ks][nt] = *(const short8*)&B_s[row * 64 + (((ks * 4 + fq) ^ sw) << 3)];
        }
#pragma unroll
        for (int ks = 0; ks < 2; ++ks)
#pragma unroll
            for (int mt = 0; mt < MT; ++mt)
#pragma unroll
                for (int nt = 0; nt < 4; ++nt)
                    acc[mt][nt] = __builtin_amdgcn_mfma_f32_16x16x32_bf16(
                        av[ks][mt], bv[ks][nt], acc[mt][nt], 0, 0, 0);
    }

    // epilogue: D row = fq*4+reg, col = fm (verified r4-r7)
#pragma unroll
    for (int mt = 0; mt < MT; mt++) {
        int row0 = bm + wr * (BM / 2) + mt * 16 + fq * 4;
#pragma unroll
        for (int nt = 0; nt < 4; nt++) {
            int col = bn + wc * 64 + nt * 16 + fm;
            float bsv = bias[col];
#pragma unroll
            for (int r = 0; r < 4; r++) {
                float val = acc[mt][nt][r] + bsv;
                if (RELU) val = fmaxf(val, 0.f);
                if constexpr (sizeof(TC) == 4)
                    ((float*)C)[(size_t)(row0 + r) * N + col] = val;
                else
                    ((ushort*)C)[(size_t)(row0 + r) * N + col] = f2bf(val);
            }
        }
    }
}

// ---------- flash-style attention with distance decay (bf16 in/out) ----------
// LDS: QP (Q tile, later P tile — disjoint lifetimes) + Ks + Vts = 27.6 KB
// -> 4-5 blocks/CU (vs 2 at r7's 62.5 KB): latency-bound scan chain hidden.
__global__ __launch_bounds__(256, 4) void attn_flash(
    const ushort* __restrict__ Q, const ushort* __restrict__ Kg,
    const ushort* __restrict__ Vg, const float* __restrict__ gammas,
    const int* __restrict__ maskp, ushort* __restrict__ out) {
    __shared__ short QP[64 * 72];        // 9.2 KB: Q tile [i][d]; pass2: P tiles
    __shared__ short Ks[JC2 * 72];       // 9.2 KB: K chunk [j][d]
    __shared__ short Vts[64 * 72];       // 9.2 KB: V chunk transposed [d][j]

    const int t = threadIdx.x;
    const int lane = t & 63, w = t >> 6;
    const int col = lane & 15;
    const int quad = lane >> 4;

    const int bid = blockIdx.x;          // ((b*H)+h)*16 + it
    const int it = bid & 15;
    const int bh = bid >> 4;
    const int h = bh & (HH - 1);
    const int b = bh >> 4;
    const int i0 = it * 64;
    const int mask = *maskp;

    const float g0 = gammas[h];
    const float gamma = -((g0 > 20.f) ? g0 : log1pf(__expf(g0)));

    const size_t qbase = ((size_t)(b * SS + i0)) * DDIM + h * DKK;
    const size_t kvbase = ((size_t)b * SS) * DDIM + h * DKK;

    {   // stage Q tile into QP
        int r = t >> 2, d0 = (t & 3) << 4;
        const ushort* gq = Q + qbase + (size_t)r * DDIM + d0;
        *(short8*)&QP[r * 72 + d0]     = *(const short8*)(gq);
        *(short8*)&QP[r * 72 + d0 + 8] = *(const short8*)(gq + 8);
    }
    __syncthreads();
    const short8 qa0 = *(const short8*)&QP[(w * 16 + col) * 72 + quad * 8];
    const short8 qa1 = *(const short8*)&QP[(w * 16 + col) * 72 + 32 + quad * 8];
    // QP is dead as Q from here; reused as P tiles in pass 2 (after barriers).

    float m1[4], su[4], smT[4], gi4[4];
    int lim4[4];
#pragma unroll
    for (int r = 0; r < 4; ++r) {
        m1[r] = -3.4e38f; su[r] = 0.f; smT[r] = 0.f;
        int gi = i0 + w * 16 + quad * 4 + r;
        gi4[r] = (float)gi;
        lim4[r] = gi + mask;
    }

    // ======== pass 1: online (max, unmasked sum, masked sum) ========
    for (int ck = 0; ck < SS / JC2; ++ck) {
        const int jc = ck * JC2;
        __syncthreads();
        {   // stage K chunk (64 x 64)
            int j = t >> 2, d0 = (t & 3) << 4;
            const ushort* gk = Kg + kvbase + (size_t)(jc + j) * DDIM + d0;
            *(short8*)&Ks[j * 72 + d0]     = *(const short8*)(gk);
            *(short8*)&Ks[j * 72 + d0 + 8] = *(const short8*)(gk + 8);
        }
        __syncthreads();
#pragma unroll
        for (int g = 0; g < 4; ++g) {
            short8 kb0 = *(const short8*)&Ks[(g * 16 + col) * 72 + quad * 8];
            short8 kb1 = *(const short8*)&Ks[(g * 16 + col) * 72 + 32 + quad * 8];
            f32x4 c = (f32x4){0.f, 0.f, 0.f, 0.f};
            c = __builtin_amdgcn_mfma_f32_16x16x32_bf16(qa0, kb0, c, 0, 0, 0);
            c = __builtin_amdgcn_mfma_f32_16x16x32_bf16(qa1, kb1, c, 0, 0, 0);
            int j = jc + g * 16 + col;
#pragma unroll
            for (int r = 0; r < 4; ++r) {
                float s = c[r] * 0.125f;
                float mn = fmaxf(m1[r], s);
                float esc = __expf(m1[r] - mn);
                float ev = __expf(s - mn);
                su[r] = su[r] * esc + ev;
                smT[r] = smT[r] * esc + ((j < lim4[r]) ? ev : 0.f);
                m1[r] = mn;
            }
        }
    }
#pragma unroll
    for (int off = 1; off < 16; off <<= 1) {
#pragma unroll
        for (int r = 0; r < 4; ++r) {
            float mo = __shfl_xor(m1[r], off, 16);
            float so = __shfl_xor(su[r], off, 16);
            float to = __shfl_xor(smT[r], off, 16);
            float M = fmaxf(m1[r], mo);
            float e1 = __expf(m1[r] - M), e2 = __expf(mo - M);
            su[r] = su[r] * e1 + so * e2;
            smT[r] = smT[r] * e1 + to * e2;
            m1[r] = M;
        }
    }
    float invu[4];
#pragma unroll
    for (int r = 0; r < 4; ++r) invu[r] = 1.f / su[r];

    // ======== pass 2: recompute + cumsum + decay + online softmax#2 + PV ====
    float m2[4], l2[4], carry[4];
    f32x4 o[4];
#pragma unroll
    for (int r = 0; r < 4; ++r) { m2[r] = -3.4e38f; l2[r] = 0.f; carry[r] = 0.f; }
#pragma unroll
    for (int dg = 0; dg < 4; ++dg) o[dg] = (f32x4){0.f, 0.f, 0.f, 0.f};

    short* Pw = &QP[w * 16 * 72];

    for (int ck = 0; ck < SS / JC2; ++ck) {
        const int jc = ck * JC2;
        __syncthreads();
        {   // stage K chunk
            int j = t >> 2, d0 = (t & 3) << 4;
            const ushort* gk = Kg + kvbase + (size_t)(jc + j) * DDIM + d0;
            *(short8*)&Ks[j * 72 + d0]     = *(const short8*)(gk);
            *(short8*)&Ks[j * 72 + d0 + 8] = *(const short8*)(gk + 8);
        }
        {   // stage V chunk transposed: Vts[d][j], j = lane-major
            int j = t & 63, dq = t >> 6, d0 = dq * 16;
            const ushort* gv = Vg + kvbase + (size_t)(jc + j) * DDIM + d0;
            short8 v0 = *(const short8*)(gv);
            short8 v1 = *(const short8*)(gv + 8);
#pragma unroll
            for (int k = 0; k < 8; ++k) {
                Vts[(d0 + k) * 72 + j]     = v0[k];
                Vts[(d0 + 8 + k) * 72 + j] = v1[k];
            }
        }
        __syncthreads();

        f32x4 sf[4];
        float cm[4] = {-3.4e38f, -3.4e38f, -3.4e38f, -3.4e38f};
#pragma unroll
        for (int g = 0; g < 4; ++g) {
            short8 kb0 = *(const short8*)&Ks[(g * 16 + col) * 72 + quad * 8];
            short8 kb1 = *(const short8*)&Ks[(g * 16 + col) * 72 + 32 + quad * 8];
            f32x4 c = (f32x4){0.f, 0.f, 0.f, 0.f};
            c = __builtin_amdgcn_mfma_f32_16x16x32_bf16(qa0, kb0, c, 0, 0, 0);
            c = __builtin_amdgcn_mfma_f32_16x16x32_bf16(qa1, kb1, c, 0, 0, 0);
            int j = jc + g * 16 + col;
            float sv[4], incl[4];
#pragma unroll
            for (int r = 0; r < 4; ++r) {
                sv[r] = c[r] * 0.125f;
                float p = __expf(sv[r] - m1[r]);
                incl[r] = (j < lim4[r]) ? p : 0.f;
            }
#pragma unroll
            for (int dd = 1; dd < 16; dd <<= 1) {
#pragma unroll
                for (int r = 0; r < 4; ++r) {
                    float tv = __shfl_up(incl[r], dd, 16);
                    if (col >= dd) incl[r] += tv;
                }
            }
#pragma unroll
            for (int r = 0; r < 4; ++r) {
                float grptot = __shfl(incl[r], 15, 16);
                float Cc = carry[r] + incl[r];
                carry[r] += grptot;
                float pos = fabsf((float)j - gi4[r]);
                float d2 = fmaxf((smT[r] - Cc) * invu[r] * pos, 0.f);
                float eff = fminf(fmaxf(__expf(gamma * sqrtf(d2)), 1e-5f), 1e5f);
                float sp = (j < lim4[r]) ? sv[r] * eff : -1e20f;
                sf[g][r] = sp;
                cm[r] = fmaxf(cm[r], sp);
            }
        }
#pragma unroll
        for (int off = 1; off < 16; off <<= 1)
#pragma unroll
            for (int r = 0; r < 4; ++r)
                cm[r] = fmaxf(cm[r], __shfl_xor(cm[r], off, 16));
        float alpha[4], padd[4];
#pragma unroll
        for (int r = 0; r < 4; ++r) {
            float mn = fmaxf(m2[r], cm[r]);
            alpha[r] = __expf(m2[r] - mn);
            m2[r] = mn;
            l2[r] *= alpha[r];
            padd[r] = 0.f;
        }
#pragma unroll
        for (int dg = 0; dg < 4; ++dg)
#pragma unroll
            for (int r = 0; r < 4; ++r) o[dg][r] *= alpha[r];
#pragma unroll
        for (int g = 0; g < 4; ++g)
#pragma unroll
            for (int r = 0; r < 4; ++r) {
                float p = __expf(sf[g][r] - m2[r]);
                padd[r] += p;
                Pw[(quad * 4 + r) * 72 + g * 16 + col] = (short)f2bf(p);
            }
#pragma unroll
        for (int off = 1; off < 16; off <<= 1)
#pragma unroll
            for (int r = 0; r < 4; ++r) padd[r] += __shfl_xor(padd[r], off, 16);
#pragma unroll
        for (int r = 0; r < 4; ++r) l2[r] += padd[r];
        __syncthreads();   // P writes visible (cross-lane A-frag reads)
#pragma unroll
        for (int kg = 0; kg < 2; ++kg) {
            short8 pa = *(const short8*)&Pw[col * 72 + kg * 32 + quad * 8];
#pragma unroll
            for (int dg = 0; dg < 4; ++dg) {
                short8 vb = *(const short8*)&Vts[(dg * 16 + col) * 72 + kg * 32 + quad * 8];
                o[dg] = __builtin_amdgcn_mfma_f32_16x16x32_bf16(pa, vb, o[dg], 0, 0, 0);
            }
        }
    }

#pragma unroll
    for (int r = 0; r < 4; ++r) {
        int irow = i0 + w * 16 + quad * 4 + r;
        float scl = 1.f / l2[r];
        if (mask == 0 && irow == 0) scl = 0.f;
        size_t base = ((size_t)(b * SS) + irow) * DDIM + h * DKK;
#pragma unroll
        for (int dg = 0; dg < 4; ++dg)
            out[base + dg * 16 + col] = f2bf(o[dg][r] * scl);
    }
}

// ---------- fused residual-add + LayerNorm (+ optional bf16 copy) ----------
template <bool WB>
__global__ __launch_bounds__(256) void add_ln(const float* __restrict__ R,
                                              const float* __restrict__ Y,
                                              const float* __restrict__ w,
                                              const float* __restrict__ bb,
                                              float* __restrict__ out,
                                              ushort* __restrict__ obf) {
    const int row = blockIdx.x;
    const int tid = threadIdx.x;
    __shared__ float red[4];
    __shared__ float xs[DDIM];
    const size_t base = (size_t)row * DDIM;
    float s = 0.f, s2 = 0.f;
#pragma unroll
    for (int l = 0; l < 4; l++) {
        int idx = tid + l * 256;
        float x = R[base + idx] + Y[base + idx];
        xs[idx] = x;
        s += x;
        s2 += x * x;
    }
    s = block_reduce_sum(s, red, tid);
    s2 = block_reduce_sum(s2, red, tid);
    const float mu = s * (1.f / DDIM);
    const float var = s2 * (1.f / DDIM) - mu * mu;
    const float rstd = rsqrtf(var + 1e-5f);
#pragma unroll
    for (int l = 0; l < 4; l++) {
        int idx = tid + l * 256;
        float v = (xs[idx] - mu) * rstd * w[idx] + bb[idx];
        out[base + idx] = v;
        if (WB) obf[base + idx] = f2bf(v);
    }
}

extern "C" void kernel_launch(void* const* d_in, const int* in_sizes, int n_in,
                              void* d_out, int out_size, void* d_ws, size_t ws_size,
                              hipStream_t stream) {
    const int*   maskp  = (const int*)d_in[0];
    const float* query  = (const float*)d_in[1];
    const float* key    = (const float*)d_in[2];
    const float* values = (const float*)d_in[3];
    const float* Wq = (const float*)d_in[4];
    const float* bq = (const float*)d_in[5];
    const float* Wk = (const float*)d_in[6];
    const float* bk = (const float*)d_in[7];
    const float* Wv = (const float*)d_in[8];
    const float* bv = (const float*)d_in[9];
    const float* Wo = (const float*)d_in[10];
    const float* bo = (const float*)d_in[11];
    const float* gammas = (const float*)d_in[12];
    const float* ln1w = (const float*)d_in[13];
    const float* ln1b = (const float*)d_in[14];
    const float* W1 = (const float*)d_in[15];
    const float* b1 = (const float*)d_in[16];
    const float* W2 = (const float*)d_in[17];
    const float* b2 = (const float*)d_in[18];
    const float* ln2w = (const float*)d_in[19];
    const float* ln2b = (const float*)d_in[20];

    const int M = BB * SS;                 // 4096 rows
    const size_t MB = 1048576;
    char* wsb = (char*)d_ws;
    ushort* Wq_bf = (ushort*)(wsb + 0 * MB);
    ushort* Wk_bf = (ushort*)(wsb + 8 * MB);
    ushort* Wv_bf = (ushort*)(wsb + 16 * MB);
    ushort* Wo_bf = (ushort*)(wsb + 24 * MB);
    ushort* W1_bf = (ushort*)(wsb + 32 * MB);
    ushort* W2_bf = (ushort*)(wsb + 40 * MB);
    ushort* qi_bf = (ushort*)(wsb + 48 * MB);
    ushort* ki_bf = (ushort*)(wsb + 56 * MB);
    ushort* vi_bf = (ushort*)(wsb + 64 * MB);
    ushort* Qb    = (ushort*)(wsb + 72 * MB);
    ushort* Kb    = (ushort*)(wsb + 80 * MB);
    ushort* Vb    = (ushort*)(wsb + 88 * MB);
    ushort* ATTb  = (ushort*)(wsb + 96 * MB);
    float*  Yf    = (float*)(wsb + 104 * MB);
    float*  xf    = (float*)(wsb + 48 * MB);    // alias qi/ki (dead after QKV)
    ushort* x_bf  = (ushort*)(wsb + 64 * MB);   // alias vi
    ushort* hidden= (ushort*)(wsb + 72 * MB);   // alias Q/K/V/ATT (dead)

    dim3 blk(256);

    // batch convert fp32 -> bf16 with correct per-segment sizes
    const unsigned int N4M = 4u * 1024 * 1024, N1M = 1024 * 1024;
    CvtArgs ca;
    ca.s[0] = query; ca.s[1] = key; ca.s[2] = values;
    ca.s[3] = Wq; ca.s[4] = Wk; ca.s[5] = Wv; ca.s[6] = Wo;
    ca.s[7] = W1; ca.s[8] = W2;
    ca.d[0] = qi_bf; ca.d[1] = ki_bf; ca.d[2] = vi_bf;
    ca.d[3] = Wq_bf; ca.d[4] = Wk_bf; ca.d[5] = Wv_bf; ca.d[6] = Wo_bf;
    ca.d[7] = W1_bf; ca.d[8] = W2_bf;
    ca.n[0] = N4M; ca.n[1] = N4M; ca.n[2] = N4M;
    ca.n[3] = N1M; ca.n[4] = N1M; ca.n[5] = N1M; ca.n[6] = N1M;
    ca.n[7] = N4M; ca.n[8] = N4M;
    convert_bf<<<dim3(2048, 9), blk, 0, stream>>>(ca);

    // QKV projections -> bf16
    gemm_bf<64, ushort, false><<<dim3(8, 64), blk, 0, stream>>>(qi_bf, Wq_bf, bq, Qb, M, DDIM, DDIM);
    gemm_bf<64, ushort, false><<<dim3(8, 64), blk, 0, stream>>>(ki_bf, Wk_bf, bk, Kb, M, DDIM, DDIM);
    gemm_bf<64, ushort, false><<<dim3(8, 64), blk, 0, stream>>>(vi_bf, Wv_bf, bv, Vb, M, DDIM, DDIM);

    // attention (flash-style, bf16 in/out)
    attn_flash<<<dim3(BB * HH * 16), blk, 0, stream>>>(Qb, Kb, Vb, gammas, maskp, ATTb);

    // output projection -> fp32 Y
    gemm_bf<64, float, false><<<dim3(8, 64), blk, 0, stream>>>(ATTb, Wo_bf, bo, Yf, M, DDIM, DDIM);

    // x = LN(query + Y) -> xf fp32 + x_bf
    add_ln<true><<<dim3(M), blk, 0, stream>>>(query, Yf, ln1w, ln1b, xf, x_bf);

    // hidden = relu(x @ W1^T + b1) -> bf16
    gemm_bf<128, ushort, true><<<dim3(32, 32), blk, 0, stream>>>(x_bf, W1_bf, b1, hidden, M, DFFF, DDIM);

    // y = hidden @ W2^T + b2 -> fp32 Y
    gemm_bf<64, float, false><<<dim3(8, 64), blk, 0, stream>>>(hidden, W2_bf, b2, Yf, M, DDIM, DFFF);

    // out = LN(x + y) -> d_out (fp32)
    add_ln<false><<<dim3(M), blk, 0, stream>>>(xf, Yf, ln2w, ln2b, (float*)d_out, nullptr);
}